// Round 5
// baseline (4125.014 us; speedup 1.0000x reference)
//
#include <hip/hip_runtime.h>

typedef __attribute__((ext_vector_type(8))) short short8;
typedef __attribute__((ext_vector_type(4))) float f32x4;

__device__ __forceinline__ unsigned short f2bf(float f) {
  unsigned u = __float_as_uint(f);
  unsigned r = (u + 0x7fffu + ((u >> 16) & 1u)) >> 16;
  return (unsigned short)r;
}
__device__ __forceinline__ float bf2f(unsigned short h) {
  return __uint_as_float(((unsigned)h) << 16);
}

// ---------------------------------------------------------------------------
__global__ __launch_bounds__(256) void bnprep_kernel(
    const float* __restrict__ g, const float* __restrict__ be,
    const float* __restrict__ m, const float* __restrict__ v,
    const float* __restrict__ b, float* __restrict__ A, float* __restrict__ C, int n)
{
  int i = blockIdx.x * 256 + threadIdx.x;
  if (i < n) {
    float s = g[i] / sqrtf(v[i] + 1e-5f);
    A[i] = s;
    C[i] = (b[i] - m[i]) * s + be[i];
  }
}

// Pre-pack conv weights into MFMA B-fragment order:
// unit = (s*NCB + cb)*NF + f ; halves addr = unit*1024 + plane*512 + lane*8 + j
__global__ __launch_bounds__(256) void wprep2_kernel(
    const float* __restrict__ w, unsigned short* __restrict__ wPk, int CO, int CI)
{
  int NCB = CI / 32, NF = CO / 16;
  int total = 9 * NCB * NF * 64;
  int idx = blockIdx.x * 256 + threadIdx.x;
  if (idx >= total) return;
  int lane = idx & 63;
  int unit = idx >> 6;
  int f = unit % NF;
  int cb = (unit / NF) % NCB;
  int s = unit / (NF * NCB);
  int co = f * 16 + (lane & 15);
  int ci0 = cb * 32 + (lane >> 4) * 8;
  long base = (long)unit * 1024 + lane * 8;
  #pragma unroll
  for (int j = 0; j < 8; ++j) {
    float v = w[((long)co * CI + ci0 + j) * 9 + s];
    unsigned short h = f2bf(v);
    unsigned short l = f2bf(v - bf2f(h));
    wPk[base + j] = h;
    wPk[base + 512 + j] = l;
  }
}

// conv1: 3->32, 32x32, fp32 compute, emits channel-last split-bf16.
__global__ __launch_bounds__(256) void conv1_kernel(
    const float* __restrict__ in, const float* __restrict__ wgt,
    const float* __restrict__ Ap, const float* __restrict__ Cp,
    unsigned short* __restrict__ out)
{
  __shared__ alignas(16) float smem[3 * 432 + 864];
  const int tid = threadIdx.x;
  const int img = blockIdx.x;
  const int by = (blockIdx.y >> 1) * 16, bx = (blockIdx.y & 1) * 16;
  const int r0 = (tid & 63) >> 4, xx = tid & 15, cog = tid >> 6;

  float acc[4][8];
  #pragma unroll
  for (int i = 0; i < 4; ++i)
    #pragma unroll
    for (int j = 0; j < 8; ++j) acc[i][j] = 0.f;

  for (int e = tid; e < 972; e += 256) {
    int ci = e / 324, rem = e - ci * 324;
    int rr = rem / 18, cc = rem - rr * 18;
    int gy = by + rr - 1, gx = bx + cc - 1;
    float v = 0.f;
    if (gy >= 0 && gy < 32 && gx >= 0 && gx < 32)
      v = in[(long)img * 3072 + ci * 1024 + gy * 32 + gx];
    smem[ci * 432 + rr * 24 + cc] = v;
  }
  for (int e = tid; e < 864; e += 256) {
    int co = e & 31, rem = e >> 5;
    smem[1296 + rem * 32 + co] = wgt[(long)co * 27 + rem];
  }
  __syncthreads();
  for (int ci = 0; ci < 3; ++ci) {
    #pragma unroll
    for (int k = 0; k < 9; ++k) {
      int ky = k / 3, kx = k - 3 * (k / 3);
      const float4* w4 = (const float4*)(smem + 1296 + (ci * 9 + k) * 32 + cog * 8);
      float4 w0 = w4[0], w1 = w4[1];
      #pragma unroll
      for (int i = 0; i < 4; ++i) {
        float iv = smem[ci * 432 + (r0 + 4 * i + ky) * 24 + xx + kx];
        acc[i][0] += iv * w0.x; acc[i][1] += iv * w0.y;
        acc[i][2] += iv * w0.z; acc[i][3] += iv * w0.w;
        acc[i][4] += iv * w1.x; acc[i][5] += iv * w1.y;
        acc[i][6] += iv * w1.z; acc[i][7] += iv * w1.w;
      }
    }
  }
  #pragma unroll
  for (int j = 0; j < 8; ++j) {
    int co = cog * 8 + j;
    float Ar = Ap[co], Cr = Cp[co];
    #pragma unroll
    for (int i = 0; i < 4; ++i) {
      float vv = fmaxf(acc[i][j] * Ar + Cr, 0.f);
      unsigned short h = f2bf(vv);
      unsigned short l = f2bf(vv - bf2f(h));
      long px = (long)img * 1024 + (by + r0 + 4 * i) * 32 + bx + xx;
      out[px * 64 + co] = h;
      out[px * 64 + 32 + co] = l;
    }
  }
}

// ---------------------------------------------------------------------------
// Split-bf16 MFMA conv v3: 512-thr / 8-wave blocks, waves split px x co
// (NPXG x NCOG). Block covers COB channels of every pixel it touches ->
// full-line writes, minimal A re-fetch. A in 8-plane LDS layout
// (conflict-free 16B-stride reads). B fragments from global (L1/L2-resident).
// MODE 0: plain store; 1: fused 2x2 maxpool store; 2: pool + global avg.
template<int H, int CI, int CO, int COB, int TY, int TX, int MODE>
__global__ __launch_bounds__(512, 4) void convmf3_kernel(
    const unsigned short* __restrict__ actIn, const unsigned short* __restrict__ wPk,
    const float* __restrict__ Ap, const float* __restrict__ Cp,
    void* __restrict__ outP)
{
  constexpr int NCB = CI / 32;
  constexpr int NF  = CO / 16;
  constexpr int NCOG = COB / 64;
  constexpr int NPXG = 8 / NCOG;
  constexpr int ROWS_PG = TY / NPXG;
  constexpr int FRX = TX / 16;
  constexpr int PXW = TX + 2;
  constexpr int PXT = (TY + 2) * PXW;
  constexpr int PLSTR = PXT * 8 + 8;       // halves; +8 staggers plane banks
  constexpr int TILES_Y = H / TY;
  constexpr int CBLK = CO / COB;
  constexpr int TPI = TILES_Y * CBLK;
  constexpr int PIX_IN = 2 * CI;
  __shared__ alignas(16) unsigned short smem[8 * PLSTR];

  // bijective XCD-chunked swizzle: sibling blocks (same img) share an XCD L2
  const int nwg = gridDim.x;
  const int orig = blockIdx.x;
  const int q = nwg >> 3, r = nwg & 7;
  const int xcd = orig & 7, pos = orig >> 3;
  const int bx = (xcd < r ? xcd * (q + 1) : r * (q + 1) + (xcd - r) * q) + pos;

  const int img = bx / TPI;
  const int sub = bx % TPI;
  const int tY0 = (sub % TILES_Y) * TY;
  const int blkco = sub / TILES_Y;

  const int tid = threadIdx.x;
  const int lane = tid & 63;
  const int lx = lane & 15, kg = lane >> 4;
  const int w = tid >> 6;
  const int pxg = w % NPXG, cog = w / NPXG;

  f32x4 acc[4][4];
  #pragma unroll
  for (int i = 0; i < 4; ++i)
    #pragma unroll
    for (int j = 0; j < 4; ++j) acc[i][j] = (f32x4){0.f, 0.f, 0.f, 0.f};

  for (int cb = 0; cb < NCB; ++cb) {
    if (cb) __syncthreads();
    // stage A tile (halo, zero-padded) into 8 ci-planes
    for (int t2 = tid; t2 < PXT * 8; t2 += 512) {
      int px = t2 >> 3, c = t2 & 7;
      int ry = px / PXW, rx = px - ry * PXW;
      int gy = tY0 + ry - 1, gx = rx - 1;
      float4 v = (float4){0.f, 0.f, 0.f, 0.f};
      if (gy >= 0 && gy < H && gx >= 0 && gx < H) {
        int coff = (c < 4) ? (cb * 32 + c * 8) : (CI + cb * 32 + (c - 4) * 8);
        v = *(const float4*)(actIn + ((long)img * H * H + gy * H + gx) * PIX_IN + coff);
      }
      *(float4*)(smem + c * PLSTR + px * 8) = v;
    }
    __syncthreads();

    for (int s = 0; s < 9; ++s) {
      const int ky = s / 3, kx = s - 3 * (s / 3);
      const long ub = ((long)(s * NCB + cb) * NF + blkco * (COB / 16) + cog * 4) * 1024
                      + lane * 8;
      short8 bh[4], bl[4];
      #pragma unroll
      for (int nf = 0; nf < 4; ++nf) {
        bh[nf] = *(const short8*)(wPk + ub + nf * 1024);
        bl[nf] = *(const short8*)(wPk + ub + nf * 1024 + 512);
      }
      #pragma unroll
      for (int mf = 0; mf < 4; ++mf) {
        const int yoff = (FRX == 2) ? (mf >> 1) : mf;
        const int xb = (FRX == 2) ? ((mf & 1) * 16) : 0;
        const int y = pxg * ROWS_PG + yoff;
        const int pxa = (y + ky) * PXW + xb + kx + lx;
        short8 ah = *(const short8*)(smem + kg * PLSTR + pxa * 8);
        short8 al = *(const short8*)(smem + (kg + 4) * PLSTR + pxa * 8);
        #pragma unroll
        for (int nf = 0; nf < 4; ++nf)
          acc[mf][nf] = __builtin_amdgcn_mfma_f32_16x16x32_bf16(ah, bh[nf], acc[mf][nf], 0, 0, 0);
        #pragma unroll
        for (int nf = 0; nf < 4; ++nf)
          acc[mf][nf] = __builtin_amdgcn_mfma_f32_16x16x32_bf16(ah, bl[nf], acc[mf][nf], 0, 0, 0);
        #pragma unroll
        for (int nf = 0; nf < 4; ++nf)
          acc[mf][nf] = __builtin_amdgcn_mfma_f32_16x16x32_bf16(al, bh[nf], acc[mf][nf], 0, 0, 0);
      }
    }
  }

  // ---- epilogue. D frag: px = 4*kg + reg (within 16-px frag), co-lane = lx.
  float Ar[4], Cr[4];
  #pragma unroll
  for (int nf = 0; nf < 4; ++nf) {
    int co = blkco * COB + cog * 64 + nf * 16 + lx;
    Ar[nf] = Ap[co]; Cr[nf] = Cp[co];
  }

  if (MODE == 0) {
    unsigned short* outA = (unsigned short*)outP;
    #pragma unroll
    for (int mf = 0; mf < 4; ++mf) {
      int y = tY0 + pxg * ROWS_PG + mf;
      #pragma unroll
      for (int rr = 0; rr < 4; ++rr) {
        int x = 4 * kg + rr;
        long apx = ((long)img * H * H + y * H + x) * (2 * CO);
        #pragma unroll
        for (int nf = 0; nf < 4; ++nf) {
          float vv = fmaxf(acc[mf][nf][rr] * Ar[nf] + Cr[nf], 0.f);
          unsigned short h = f2bf(vv);
          unsigned short l = f2bf(vv - bf2f(h));
          int co = blkco * COB + cog * 64 + nf * 16 + lx;
          outA[apx + co] = h;
          outA[apx + CO + co] = l;
        }
      }
    }
  } else if (MODE == 1) {
    // fused 2x2 maxpool: y-pairs = (mf, mf+2) [FRX=2], x-pairs = reg pairs
    unsigned short* outA = (unsigned short*)outP;
    #pragma unroll
    for (int xf = 0; xf < 2; ++xf) {
      #pragma unroll
      for (int rp = 0; rp < 2; ++rp) {
        int py = (tY0 >> 1) + pxg;
        int x = xf * 8 + 2 * kg + rp;
        long apx = ((long)img * (H * H / 4) + py * (H / 2) + x) * (2 * CO);
        #pragma unroll
        for (int nf = 0; nf < 4; ++nf) {
          float v0 = fmaxf(fmaxf(acc[xf][nf][2 * rp], acc[xf][nf][2 * rp + 1]),
                           fmaxf(acc[xf + 2][nf][2 * rp], acc[xf + 2][nf][2 * rp + 1]));
          float vv = fmaxf(v0 * Ar[nf] + Cr[nf], 0.f);
          unsigned short h = f2bf(vv);
          unsigned short l = f2bf(vv - bf2f(h));
          int co = nf * 16 + lx;
          outA[apx + co] = h;
          outA[apx + CO + co] = l;
        }
      }
    }
  } else {
    // 2x2 maxpool + BN/ReLU + global average -> feats
    float psum[4] = {0.f, 0.f, 0.f, 0.f};
    #pragma unroll
    for (int nf = 0; nf < 4; ++nf) {
      #pragma unroll
      for (int mfp = 0; mfp < 2; ++mfp) {
        #pragma unroll
        for (int rp = 0; rp < 2; ++rp) {
          float v = fmaxf(fmaxf(acc[2 * mfp][nf][2 * rp], acc[2 * mfp][nf][2 * rp + 1]),
                          fmaxf(acc[2 * mfp + 1][nf][2 * rp], acc[2 * mfp + 1][nf][2 * rp + 1]));
          psum[nf] += fmaxf(v * Ar[nf] + Cr[nf], 0.f);
        }
      }
    }
    #pragma unroll
    for (int nf = 0; nf < 4; ++nf) {
      psum[nf] += __shfl_xor(psum[nf], 16);
      psum[nf] += __shfl_xor(psum[nf], 32);
    }
    __syncthreads();
    float* sR = (float*)smem;
    if (kg == 0) {
      #pragma unroll
      for (int nf = 0; nf < 4; ++nf) sR[w * 64 + nf * 16 + lx] = psum[nf];
    }
    __syncthreads();
    if (tid < COB) {
      int ct = tid >> 6, ci_ = tid & 63;
      float s = 0.f;
      #pragma unroll
      for (int p = 0; p < NPXG; ++p) s += sR[(ct * NPXG + p) * 64 + ci_];
      ((float*)outP)[(long)img * 256 + blkco * COB + tid] = s * (1.f / 64.f);
    }
  }
}

// ---------------------------------------------------------------------------
// heads / sort / routing / combine (unchanged)
__global__ __launch_bounds__(256) void heads2_kernel(
    const float* __restrict__ feats, const float* __restrict__ gw1,
    const float* __restrict__ gb1, const float* __restrict__ gw2,
    const float* __restrict__ gb2, const float* __restrict__ clsw,
    const float* __restrict__ clsb, const float* __restrict__ usage,
    float* __restrict__ logits_e, float* __restrict__ rs_out)
{
  __shared__ float sF[64 * 257];
  __shared__ float sLg[4 * 64 * 10];
  __shared__ float sRed[4 * 64];
  const int tid = threadIdx.x;
  const int b0 = blockIdx.x * 64;
  const int e  = blockIdx.y;

  for (int idx = tid; idx < 64 * 64; idx += 256) {
    int t = idx >> 6, dg = idx & 63;
    float4 v = ((const float4*)(feats + (long)(b0 + t) * 256))[dg];
    float* p = sF + t * 257 + dg * 4;
    p[0] = v.x; p[1] = v.y; p[2] = v.z; p[3] = v.w;
  }
  __syncthreads();

  const int t  = tid & 63;
  const int hw = __builtin_amdgcn_readfirstlane(tid >> 6);

  {
    float acc[10];
    #pragma unroll
    for (int c = 0; c < 10; ++c) acc[c] = 0.f;
    const float* fp = sF + t * 257 + hw * 64;
    const float* cw = clsw + (long)e * 2560 + hw * 64;
    for (int dd = 0; dd < 64; ++dd) {
      float f = fp[dd];
      #pragma unroll
      for (int c = 0; c < 10; ++c) acc[c] += f * cw[c * 256 + dd];
    }
    #pragma unroll
    for (int c = 0; c < 10; ++c) sLg[(hw * 64 + t) * 10 + c] = acc[c];
  }
  {
    float gacc[32];
    #pragma unroll
    for (int j = 0; j < 32; ++j) gacc[j] = 0.f;
    const float* wb = gw1 + ((long)e * 256) * 128 + hw * 32;
    const float* fp = sF + t * 257;
    for (int d = 0; d < 256; ++d) {
      float f = fp[d];
      const float4* w4 = (const float4*)(wb + (long)d * 128);
      #pragma unroll
      for (int qq = 0; qq < 8; ++qq) {
        float4 wv = w4[qq];
        gacc[4 * qq + 0] += f * wv.x; gacc[4 * qq + 1] += f * wv.y;
        gacc[4 * qq + 2] += f * wv.z; gacc[4 * qq + 3] += f * wv.w;
      }
    }
    float s = 0.f;
    const float* b1 = gb1 + e * 128 + hw * 32;
    const float* w2 = gw2 + e * 128 + hw * 32;
    #pragma unroll
    for (int j = 0; j < 32; ++j) s += fmaxf(gacc[j] + b1[j], 0.f) * w2[j];
    sRed[hw * 64 + t] = s;
  }
  __syncthreads();

  if (tid < 64) {
    float es = (sRed[t] + sRed[64 + t] + sRed[128 + t] + sRed[192 + t] + gb2[e]) * 0.5f;
    float lg[10];
    #pragma unroll
    for (int c = 0; c < 10; ++c)
      lg[c] = sLg[t * 10 + c] + sLg[(64 + t) * 10 + c]
            + sLg[(128 + t) * 10 + c] + sLg[(192 + t) * 10 + c] + clsb[e * 10 + c];
    float mx = lg[0];
    #pragma unroll
    for (int c = 1; c < 10; ++c) mx = fmaxf(mx, lg[c]);
    float S = 0.f, ps[10];
    #pragma unroll
    for (int c = 0; c < 10; ++c) { ps[c] = expf(lg[c] - mx); S += ps[c]; }
    float inv = 1.f / S, ent = 0.f;
    #pragma unroll
    for (int c = 0; c < 10; ++c) { float p = ps[c] * inv; ent -= p * logf(fmaxf(p, 1e-12f)); }
    float rsv = 0.6f * es + 0.4f * (-ent) - 2.0f * usage[e];
    rs_out[(long)(b0 + t) * 16 + e] = rsv;
    #pragma unroll
    for (int c = 0; c < 10; ++c)
      logits_e[((long)(b0 + t) * 16 + e) * 10 + c] = lg[c];
  }
}

__global__ __launch_bounds__(1024) void sort_kernel(
    const float* __restrict__ rs, unsigned* __restrict__ sortedIdx)
{
  __shared__ unsigned long long sk[2048];
  const int e = blockIdx.x;
  const unsigned tid = threadIdx.x;
  for (int i = tid; i < 2048; i += 1024) {
    float f = rs[(long)i * 16 + e];
    unsigned u = __float_as_uint(f);
    u ^= (u >> 31) ? 0xFFFFFFFFu : 0x80000000u;
    sk[i] = ((unsigned long long)(~u) << 32) | (unsigned)i;
  }
  for (unsigned k = 2; k <= 2048; k <<= 1) {
    for (unsigned j = k >> 1; j > 0; j >>= 1) {
      __syncthreads();
      unsigned i = ((tid & ~(j - 1)) << 1) | (tid & (j - 1));
      unsigned p = i | j;
      bool asc = ((i & k) == 0);
      unsigned long long a = sk[i], b = sk[p];
      if ((a > b) == asc) { sk[i] = b; sk[p] = a; }
    }
  }
  __syncthreads();
  for (int i = tid; i < 2048; i += 1024)
    sortedIdx[(long)e * 2048 + i] = (unsigned)(sk[i] & 0xFFFFFFFFull);
}

__global__ __launch_bounds__(1024) void routing_kernel(
    const unsigned* __restrict__ sortedIdx, const float* __restrict__ rs,
    float* __restrict__ Dout, unsigned* __restrict__ dmaskOut)
{
  __shared__ unsigned char sAvail[2048];
  __shared__ unsigned sDm[2048];
  __shared__ int sLoads[16];
  __shared__ int sWaveCnt[16];
  __shared__ int sNtc, sVC;
  const int tid = threadIdx.x;
  const int lane = tid & 63, wave = tid >> 6;
  for (int i = tid; i < 2048; i += 1024) { sAvail[i] = 1; sDm[i] = 0; }
  if (tid < 16) sLoads[tid] = 0;
  if (tid == 0) sVC = 2048;
  __syncthreads();
  for (int it = 0; it < 3; ++it) {
    for (int j = 0; j < 16; ++j) {
      if (tid == 0) {
        int rc = 256 - sLoads[j]; if (rc < 0) rc = 0;
        int vc = sVC, ntc = 0;
        if (rc > 0 && vc > 0) {
          int a = rc < vc ? rc : vc;
          int b2 = vc < 102 ? vc : 102;
          ntc = a > b2 ? a : b2;
        }
        sNtc = ntc; sLoads[j] += ntc; sVC -= ntc;
      }
      __syncthreads();
      const int ntc = sNtc;
      if (ntc > 0) {
        int base = 0;
        for (int p = 0; p < 2; ++p) {
          int i = p * 1024 + tid;
          unsigned tok = sortedIdx[(long)j * 2048 + i];
          int fl = sAvail[tok] ? 1 : 0;
          unsigned long long bm = __ballot(fl);
          if (lane == 0) sWaveCnt[wave] = __popcll(bm);
          __syncthreads();
          int off = base;
          for (int w = 0; w < wave; ++w) off += sWaveCnt[w];
          int pre = off + __popcll(bm & ((1ull << lane) - 1ull));
          if (fl && pre < ntc) { sAvail[tok] = 0; sDm[tok] |= (1u << j); }
          int tot = base;
          for (int w = 0; w < 16; ++w) tot += sWaveCnt[w];
          base = tot;
          __syncthreads();
        }
      }
      __syncthreads();
    }
  }
  if (tid == 0 && sVC > 0) {
    for (int i = 0; i < 2048; ++i) {
      if (!sAvail[i]) continue;
      float s0 = -3.4e38f, s1 = s0, s2 = s0; int e0 = 0, e1 = 0, e2 = 0;
      for (int e = 0; e < 16; ++e) {
        float s = rs[i * 16 + e];
        if (s > s0)      { s2 = s1; e2 = e1; s1 = s0; e1 = e0; s0 = s; e0 = e; }
        else if (s > s1) { s2 = s1; e2 = e1; s1 = s;  e1 = e; }
        else if (s > s2) { s2 = s;  e2 = e; }
      }
      int best = e0, bl = sLoads[e0];
      if (sLoads[e1] < bl) { best = e1; bl = sLoads[e1]; }
      if (sLoads[e2] < bl) { best = e2; bl = sLoads[e2]; }
      sDm[i] |= (1u << best);
      sLoads[best] += 1;
    }
  }
  __syncthreads();
  for (int idx = tid; idx < 2048 * 16; idx += 1024) {
    int tok = idx >> 4, e = idx & 15;
    Dout[idx] = ((sDm[tok] >> e) & 1u) ? 1.0f : 0.0f;
  }
  for (int i = tid; i < 2048; i += 1024) dmaskOut[i] = sDm[i];
}

__global__ __launch_bounds__(256) void combine_kernel(
    const unsigned* __restrict__ dmask, const float* __restrict__ rs,
    const float* __restrict__ L, float* __restrict__ out)
{
  int i = blockIdx.x * 256 + threadIdx.x;
  if (i >= 2048) return;
  unsigned dm = dmask[i];
  float r[16];
  #pragma unroll
  for (int e = 0; e < 16; ++e) r[e] = rs[i * 16 + e];
  float mx = -3.4e38f;
  #pragma unroll
  for (int e = 0; e < 16; ++e) {
    float v = ((dm >> e) & 1u) ? r[e] : 0.0f;
    mx = fmaxf(mx, v);
  }
  float w[16], S = 0.f;
  #pragma unroll
  for (int e = 0; e < 16; ++e) {
    w[e] = ((dm >> e) & 1u) ? expf(r[e] - mx) : 0.0f;
    S += w[e];
  }
  float inv = 1.f / S;
  #pragma unroll
  for (int c = 0; c < 10; ++c) {
    float a = 0.f;
    #pragma unroll
    for (int e = 0; e < 16; ++e) a += w[e] * L[((long)i * 16 + e) * 10 + c];
    out[i * 10 + c] = a * inv;
  }
}

// ---------------------------------------------------------------------------
extern "C" void kernel_launch(void* const* d_in, const int* in_sizes, int n_in,
                              void* d_out, int out_size, void* d_ws, size_t ws_size,
                              hipStream_t stream)
{
  const float* x    = (const float*)d_in[0];
  const float* cw1  = (const float*)d_in[1];
  const float* cb1  = (const float*)d_in[2];
  const float* g1   = (const float*)d_in[3];
  const float* be1  = (const float*)d_in[4];
  const float* m1   = (const float*)d_in[5];
  const float* v1   = (const float*)d_in[6];
  const float* cw2  = (const float*)d_in[7];
  const float* cb2  = (const float*)d_in[8];
  const float* g2   = (const float*)d_in[9];
  const float* be2  = (const float*)d_in[10];
  const float* m2   = (const float*)d_in[11];
  const float* v2   = (const float*)d_in[12];
  const float* cw3  = (const float*)d_in[13];
  const float* cb3  = (const float*)d_in[14];
  const float* g3   = (const float*)d_in[15];
  const float* be3  = (const float*)d_in[16];
  const float* m3   = (const float*)d_in[17];
  const float* v3   = (const float*)d_in[18];
  const float* cw4  = (const float*)d_in[19];
  const float* cb4  = (const float*)d_in[20];
  const float* g4   = (const float*)d_in[21];
  const float* be4  = (const float*)d_in[22];
  const float* m4   = (const float*)d_in[23];
  const float* v4   = (const float*)d_in[24];
  const float* gw1  = (const float*)d_in[25];
  const float* gb1  = (const float*)d_in[26];
  const float* gw2  = (const float*)d_in[27];
  const float* gb2  = (const float*)d_in[28];
  const float* clsw = (const float*)d_in[29];
  const float* clsb = (const float*)d_in[30];
  const float* usage = (const float*)d_in[31];

  float* out = (float*)d_out;
  float* ws  = (float*)d_ws;

  float* A1 = ws + 0;   float* C1 = ws + 32;
  float* A2 = ws + 64;  float* C2 = ws + 128;
  float* A3 = ws + 192; float* C3 = ws + 320;
  float* A4 = ws + 448; float* C4 = ws + 704;
  float* feats   = ws + 1024;                       // 2048*256
  float* logitsE = ws + 525312;                     // 2048*16*10
  unsigned* sortedIdx = (unsigned*)(ws + 852992);   // 16*2048
  unsigned* dmask     = (unsigned*)(ws + 885760);   // 2048
  unsigned short* wPk2 = (unsigned short*)(ws + 887808);   // 36 units  * 1024 halves
  unsigned short* wPk3 = (unsigned short*)(ws + 906240);   // 144 units * 1024
  unsigned short* wPk4 = (unsigned short*)(ws + 979968);   // 576 units * 1024
  const long bufBase = 1274880;

  long wsFloats = (long)(ws_size / 4);
  long availF = wsFloats - bufBase;
  long chunkL = availF / 49152;   // per-img: bufA 32768 f + bufB 16384 f
  int chunk = (int)(chunkL < 1 ? 1 : (chunkL > 2048 ? 2048 : chunkL));

  bnprep_kernel<<<1, 256, 0, stream>>>(g1, be1, m1, v1, cb1, A1, C1, 32);
  bnprep_kernel<<<1, 256, 0, stream>>>(g2, be2, m2, v2, cb2, A2, C2, 64);
  bnprep_kernel<<<1, 256, 0, stream>>>(g3, be3, m3, v3, cb3, A3, C3, 128);
  bnprep_kernel<<<1, 256, 0, stream>>>(g4, be4, m4, v4, cb4, A4, C4, 256);
  wprep2_kernel<<<(2304 + 255) / 256, 256, 0, stream>>>(cw2, wPk2, 64, 32);
  wprep2_kernel<<<(9216 + 255) / 256, 256, 0, stream>>>(cw3, wPk3, 128, 64);
  wprep2_kernel<<<(36864 + 255) / 256, 256, 0, stream>>>(cw4, wPk4, 256, 128);

  unsigned short* bufA = (unsigned short*)(ws + bufBase);
  unsigned short* bufB = bufA + (long)chunk * 65536;

  for (int ib = 0; ib < 2048; ib += chunk) {
    int n = 2048 - ib; if (n > chunk) n = chunk;
    conv1_kernel<<<dim3(n, 4), 256, 0, stream>>>(x + (long)ib * 3072, cw1, A1, C1, bufA);
    // conv2: 32x32, 32->64ch, 2 y-tiles/img, fused maxpool -> act2 (16x16)
    convmf3_kernel<32, 32, 64, 64, 16, 32, 1>
        <<<dim3(n * 2), 512, 0, stream>>>(bufA, wPk2, A2, C2, bufB);
    // conv3: 16x16, 64->128ch, 1 block/img, plain store -> act3
    convmf3_kernel<16, 64, 128, 128, 16, 16, 0>
        <<<dim3(n), 512, 0, stream>>>(bufB, wPk3, A3, C3, bufA);
    // conv4: 16x16, 128->256ch, 2 co-blocks/img, pool+avg -> feats
    convmf3_kernel<16, 128, 256, 128, 16, 16, 2>
        <<<dim3(n * 2), 512, 0, stream>>>(bufA, wPk4, A4, C4, feats + (long)ib * 256);
  }

  float* rsOut = out + 20480;
  heads2_kernel<<<dim3(32, 16), 256, 0, stream>>>(feats, gw1, gb1, gw2, gb2,
                                                  clsw, clsb, usage, logitsE, rsOut);
  sort_kernel<<<16, 1024, 0, stream>>>(rsOut, sortedIdx);
  routing_kernel<<<1, 1024, 0, stream>>>(sortedIdx, rsOut, out + 53248, dmask);
  combine_kernel<<<8, 256, 0, stream>>>(dmask, rsOut, logitsE, out);
}

// Round 6
// 3291.739 us; speedup vs baseline: 1.2531x; 1.2531x over previous
//
#include <hip/hip_runtime.h>

typedef __attribute__((ext_vector_type(8))) short short8;
typedef __attribute__((ext_vector_type(4))) float f32x4;

__device__ __forceinline__ unsigned short f2bf(float f) {
  unsigned u = __float_as_uint(f);
  unsigned r = (u + 0x7fffu + ((u >> 16) & 1u)) >> 16;
  return (unsigned short)r;
}
__device__ __forceinline__ float bf2f(unsigned short h) {
  return __uint_as_float(((unsigned)h) << 16);
}

// ---------------------------------------------------------------------------
__global__ __launch_bounds__(256) void bnprep_kernel(
    const float* __restrict__ g, const float* __restrict__ be,
    const float* __restrict__ m, const float* __restrict__ v,
    const float* __restrict__ b, float* __restrict__ A, float* __restrict__ C, int n)
{
  int i = blockIdx.x * 256 + threadIdx.x;
  if (i < n) {
    float s = g[i] / sqrtf(v[i] + 1e-5f);
    A[i] = s;
    C[i] = (b[i] - m[i]) * s + be[i];
  }
}

// Pre-pack conv weights into MFMA B-fragment order:
// unit = (s*NCB + cb)*NF + f ; halves addr = unit*1024 + plane*512 + lane*8 + j
__global__ __launch_bounds__(256) void wprep2_kernel(
    const float* __restrict__ w, unsigned short* __restrict__ wPk, int CO, int CI)
{
  int NCB = CI / 32, NF = CO / 16;
  int total = 9 * NCB * NF * 64;
  int idx = blockIdx.x * 256 + threadIdx.x;
  if (idx >= total) return;
  int lane = idx & 63;
  int unit = idx >> 6;
  int f = unit % NF;
  int cb = (unit / NF) % NCB;
  int s = unit / (NF * NCB);
  int co = f * 16 + (lane & 15);
  int ci0 = cb * 32 + (lane >> 4) * 8;
  long base = (long)unit * 1024 + lane * 8;
  #pragma unroll
  for (int j = 0; j < 8; ++j) {
    float v = w[((long)co * CI + ci0 + j) * 9 + s];
    unsigned short h = f2bf(v);
    unsigned short l = f2bf(v - bf2f(h));
    wPk[base + j] = h;
    wPk[base + 512 + j] = l;
  }
}

// conv1: 3->32, 32x32, fp32 compute, emits channel-last split-bf16.
__global__ __launch_bounds__(256) void conv1_kernel(
    const float* __restrict__ in, const float* __restrict__ wgt,
    const float* __restrict__ Ap, const float* __restrict__ Cp,
    unsigned short* __restrict__ out)
{
  __shared__ alignas(16) float smem[3 * 432 + 864];
  const int tid = threadIdx.x;
  const int img = blockIdx.x;
  const int by = (blockIdx.y >> 1) * 16, bx = (blockIdx.y & 1) * 16;
  const int r0 = (tid & 63) >> 4, xx = tid & 15, cog = tid >> 6;

  float acc[4][8];
  #pragma unroll
  for (int i = 0; i < 4; ++i)
    #pragma unroll
    for (int j = 0; j < 8; ++j) acc[i][j] = 0.f;

  for (int e = tid; e < 972; e += 256) {
    int ci = e / 324, rem = e - ci * 324;
    int rr = rem / 18, cc = rem - rr * 18;
    int gy = by + rr - 1, gx = bx + cc - 1;
    float v = 0.f;
    if (gy >= 0 && gy < 32 && gx >= 0 && gx < 32)
      v = in[(long)img * 3072 + ci * 1024 + gy * 32 + gx];
    smem[ci * 432 + rr * 24 + cc] = v;
  }
  for (int e = tid; e < 864; e += 256) {
    int co = e & 31, rem = e >> 5;
    smem[1296 + rem * 32 + co] = wgt[(long)co * 27 + rem];
  }
  __syncthreads();
  for (int ci = 0; ci < 3; ++ci) {
    #pragma unroll
    for (int k = 0; k < 9; ++k) {
      int ky = k / 3, kx = k - 3 * (k / 3);
      const float4* w4 = (const float4*)(smem + 1296 + (ci * 9 + k) * 32 + cog * 8);
      float4 w0 = w4[0], w1 = w4[1];
      #pragma unroll
      for (int i = 0; i < 4; ++i) {
        float iv = smem[ci * 432 + (r0 + 4 * i + ky) * 24 + xx + kx];
        acc[i][0] += iv * w0.x; acc[i][1] += iv * w0.y;
        acc[i][2] += iv * w0.z; acc[i][3] += iv * w0.w;
        acc[i][4] += iv * w1.x; acc[i][5] += iv * w1.y;
        acc[i][6] += iv * w1.z; acc[i][7] += iv * w1.w;
      }
    }
  }
  #pragma unroll
  for (int j = 0; j < 8; ++j) {
    int co = cog * 8 + j;
    float Ar = Ap[co], Cr = Cp[co];
    #pragma unroll
    for (int i = 0; i < 4; ++i) {
      float vv = fmaxf(acc[i][j] * Ar + Cr, 0.f);
      unsigned short h = f2bf(vv);
      unsigned short l = f2bf(vv - bf2f(h));
      long px = (long)img * 1024 + (by + r0 + 4 * i) * 32 + bx + xx;
      out[px * 64 + co] = h;
      out[px * 64 + 32 + co] = l;
    }
  }
}

// ---------------------------------------------------------------------------
// Split-bf16 MFMA conv (round-4 proven): 256 thr / 4 waves, 64 co per block.
// A tile in LDS, B fragments from global, LDS-transpose coalesced epilogue.
template<int H, int CI, int CO, int MODE>
__global__ __launch_bounds__(256, 3) void convmf2_kernel(
    const unsigned short* __restrict__ actIn, const unsigned short* __restrict__ wPk,
    const float* __restrict__ Ap, const float* __restrict__ Cp,
    void* __restrict__ outP)
{
  constexpr int NCB = CI / 32;
  constexpr int TILES = (H == 32) ? 4 : 1;
  constexpr int COGN = CO / 64;
  constexpr int TPI = TILES * COGN;
  constexpr int PIX_IN = 2 * CI;
  constexpr int NF = CO / 16;
  __shared__ alignas(16) unsigned short smem[23328];   // 324 x 72 halves

  const int nwg = gridDim.x;
  const int orig = blockIdx.x;
  const int q = nwg >> 3, r = nwg & 7;
  const int xcd = orig & 7, pos = orig >> 3;
  const int bx = (xcd < r ? xcd * (q + 1) : r * (q + 1) + (xcd - r) * q) + pos;

  const int img = bx / TPI;
  const int sub = bx % TPI;
  const int tY0 = (H == 32) ? ((sub >> 1) & 1) * 16 : 0;
  const int tX0 = (H == 32) ? (sub & 1) * 16 : 0;
  const int coG = (H == 32) ? 0 : sub;

  const int tid = threadIdx.x;
  const int lane = tid & 63;
  const int lx = lane & 15;
  const int kg = lane >> 4;
  const int w = tid >> 6;

  f32x4 acc[4][4];
  #pragma unroll
  for (int i = 0; i < 4; ++i)
    #pragma unroll
    for (int j = 0; j < 4; ++j) acc[i][j] = (f32x4){0.f, 0.f, 0.f, 0.f};

  for (int cb = 0; cb < NCB; ++cb) {
    if (cb) __syncthreads();
    for (int t2 = tid; t2 < 2592; t2 += 256) {
      int lp = t2 >> 3, c = t2 & 7;
      int ry = lp / 18, rx = lp - ry * 18;
      int gy = tY0 + ry - 1, gx = tX0 + rx - 1;
      float4 v = (float4){0.f, 0.f, 0.f, 0.f};
      if (gy >= 0 && gy < H && gx >= 0 && gx < H) {
        int coff = (c < 4) ? (cb * 32 + c * 8) : (CI + cb * 32 + (c - 4) * 8);
        v = *(const float4*)(actIn + ((long)img * H * H + gy * H + gx) * PIX_IN + coff);
      }
      *(float4*)(smem + lp * 72 + c * 8) = v;
    }
    __syncthreads();

    for (int s = 0; s < 9; ++s) {
      const int ky = s / 3, kx = s - 3 * (s / 3);
      const long ub = ((long)(s * NCB + cb) * NF + coG * 4) * 1024 + lane * 8;
      short8 bh[4], bl[4];
      #pragma unroll
      for (int nf = 0; nf < 4; ++nf) {
        bh[nf] = *(const short8*)(wPk + ub + nf * 1024);
        bl[nf] = *(const short8*)(wPk + ub + nf * 1024 + 512);
      }
      #pragma unroll
      for (int mf = 0; mf < 4; ++mf) {
        const unsigned short* ap = smem + ((w * 4 + mf + ky) * 18 + lx + kx) * 72 + kg * 8;
        short8 ah = *(const short8*)ap;
        short8 al = *(const short8*)(ap + 32);
        #pragma unroll
        for (int nf = 0; nf < 4; ++nf)
          acc[mf][nf] = __builtin_amdgcn_mfma_f32_16x16x32_bf16(ah, bh[nf], acc[mf][nf], 0, 0, 0);
        #pragma unroll
        for (int nf = 0; nf < 4; ++nf)
          acc[mf][nf] = __builtin_amdgcn_mfma_f32_16x16x32_bf16(ah, bl[nf], acc[mf][nf], 0, 0, 0);
        #pragma unroll
        for (int nf = 0; nf < 4; ++nf)
          acc[mf][nf] = __builtin_amdgcn_mfma_f32_16x16x32_bf16(al, bh[nf], acc[mf][nf], 0, 0, 0);
      }
    }
  }
  __syncthreads();   // A region now reusable as epilogue staging

  float ArV[4], CrV[4];
  #pragma unroll
  for (int nf = 0; nf < 4; ++nf) {
    int co = coG * 64 + nf * 16 + lx;
    ArV[nf] = Ap[co]; CrV[nf] = Cp[co];
  }

  if (MODE == 0) {
    unsigned short* outA = (unsigned short*)outP;
    unsigned short* slice = smem + w * 2048;
    #pragma unroll
    for (int mf = 0; mf < 4; ++mf) {
      int y = w * 4 + mf;
      #pragma unroll
      for (int rr = 0; rr < 4; ++rr) {
        int x = 4 * kg + rr;
        #pragma unroll
        for (int nf = 0; nf < 4; ++nf) {
          float vv = fmaxf(acc[mf][nf][rr] * ArV[nf] + CrV[nf], 0.f);
          unsigned short h = f2bf(vv);
          unsigned short l = f2bf(vv - bf2f(h));
          slice[(x * 2 + 0) * 64 + nf * 16 + lx] = h;
          slice[(x * 2 + 1) * 64 + nf * 16 + lx] = l;
        }
      }
      #pragma unroll
      for (int v = 0; v < 4; ++v) {
        int hoff = lane * 8 + v * 512;
        int x = hoff >> 7, rem = hoff & 127;
        int seg = rem >> 6, inner = rem & 63;
        short8 d = *(const short8*)(slice + hoff);
        *(short8*)(outA + ((long)img * 256 + y * 16 + x) * (2 * CO)
                   + seg * CO + coG * 64 + inner) = d;
      }
    }
  } else if (MODE == 1) {
    unsigned short* outA = (unsigned short*)outP;
    unsigned short* slice = smem + w * 1024;
    #pragma unroll
    for (int mfp = 0; mfp < 2; ++mfp) {
      int oy = (tY0 >> 1) + w * 2 + mfp;
      #pragma unroll
      for (int rp = 0; rp < 2; ++rp) {
        int oxl = 2 * kg + rp;
        #pragma unroll
        for (int nf = 0; nf < 4; ++nf) {
          float v0 = fmaxf(fmaxf(acc[2 * mfp][nf][2 * rp], acc[2 * mfp][nf][2 * rp + 1]),
                           fmaxf(acc[2 * mfp + 1][nf][2 * rp], acc[2 * mfp + 1][nf][2 * rp + 1]));
          float vv = fmaxf(v0 * ArV[nf] + CrV[nf], 0.f);
          unsigned short h = f2bf(vv);
          unsigned short l = f2bf(vv - bf2f(h));
          slice[(oxl * 2 + 0) * 64 + nf * 16 + lx] = h;
          slice[(oxl * 2 + 1) * 64 + nf * 16 + lx] = l;
        }
      }
      #pragma unroll
      for (int v = 0; v < 2; ++v) {
        int hoff = lane * 8 + v * 512;
        int oxl = hoff >> 7, rem = hoff & 127;
        int seg = rem >> 6, inner = rem & 63;
        short8 d = *(const short8*)(slice + hoff);
        *(short8*)(outA + ((long)img * 256 + oy * 16 + (tX0 >> 1) + oxl) * 128
                   + seg * 64 + inner) = d;
      }
    }
  } else {
    float psum[4] = {0.f, 0.f, 0.f, 0.f};
    #pragma unroll
    for (int nf = 0; nf < 4; ++nf) {
      #pragma unroll
      for (int mfp = 0; mfp < 2; ++mfp) {
        #pragma unroll
        for (int rp = 0; rp < 2; ++rp) {
          float v = fmaxf(fmaxf(acc[2 * mfp][nf][2 * rp], acc[2 * mfp][nf][2 * rp + 1]),
                          fmaxf(acc[2 * mfp + 1][nf][2 * rp], acc[2 * mfp + 1][nf][2 * rp + 1]));
          psum[nf] += fmaxf(v * ArV[nf] + CrV[nf], 0.f);
        }
      }
    }
    #pragma unroll
    for (int nf = 0; nf < 4; ++nf) {
      psum[nf] += __shfl_xor(psum[nf], 16);
      psum[nf] += __shfl_xor(psum[nf], 32);
    }
    __syncthreads();
    float* sR = (float*)smem;
    if (kg == 0) {
      #pragma unroll
      for (int nf = 0; nf < 4; ++nf) sR[w * 64 + nf * 16 + lx] = psum[nf];
    }
    __syncthreads();
    if (tid < 64) {
      float s = sR[tid] + sR[64 + tid] + sR[128 + tid] + sR[192 + tid];
      ((float*)outP)[(long)img * 256 + coG * 64 + tid] = s * (1.f / 64.f);
    }
  }
}

// ---------------------------------------------------------------------------
// conv4-only: 512-thr / 8-wave (4 px-groups x 2 co-groups), COB=128 -> 2
// blocks/img (halved A re-fetch). MODE 2 only: no global stores (pool+avg).
template<int H, int CI, int CO, int COB, int TY, int TX, int MODE>
__global__ __launch_bounds__(512, 4) void convmf3_kernel(
    const unsigned short* __restrict__ actIn, const unsigned short* __restrict__ wPk,
    const float* __restrict__ Ap, const float* __restrict__ Cp,
    void* __restrict__ outP)
{
  constexpr int NCB = CI / 32;
  constexpr int NF  = CO / 16;
  constexpr int NCOG = COB / 64;
  constexpr int NPXG = 8 / NCOG;
  constexpr int ROWS_PG = TY / NPXG;
  constexpr int PXW = TX + 2;
  constexpr int PXT = (TY + 2) * PXW;
  constexpr int PLSTR = PXT * 8 + 8;
  constexpr int TILES_Y = H / TY;
  constexpr int CBLK = CO / COB;
  constexpr int TPI = TILES_Y * CBLK;
  constexpr int PIX_IN = 2 * CI;
  __shared__ alignas(16) unsigned short smem[8 * PLSTR];

  const int nwg = gridDim.x;
  const int orig = blockIdx.x;
  const int q = nwg >> 3, r = nwg & 7;
  const int xcd = orig & 7, pos = orig >> 3;
  const int bx = (xcd < r ? xcd * (q + 1) : r * (q + 1) + (xcd - r) * q) + pos;

  const int img = bx / TPI;
  const int sub = bx % TPI;
  const int tY0 = (sub % TILES_Y) * TY;
  const int blkco = sub / TILES_Y;

  const int tid = threadIdx.x;
  const int lane = tid & 63;
  const int lx = lane & 15, kg = lane >> 4;
  const int w = tid >> 6;
  const int pxg = w % NPXG, cog = w / NPXG;

  f32x4 acc[4][4];
  #pragma unroll
  for (int i = 0; i < 4; ++i)
    #pragma unroll
    for (int j = 0; j < 4; ++j) acc[i][j] = (f32x4){0.f, 0.f, 0.f, 0.f};

  for (int cb = 0; cb < NCB; ++cb) {
    if (cb) __syncthreads();
    for (int t2 = tid; t2 < PXT * 8; t2 += 512) {
      int px = t2 >> 3, c = t2 & 7;
      int ry = px / PXW, rx = px - ry * PXW;
      int gy = tY0 + ry - 1, gx = rx - 1;
      float4 v = (float4){0.f, 0.f, 0.f, 0.f};
      if (gy >= 0 && gy < H && gx >= 0 && gx < H) {
        int coff = (c < 4) ? (cb * 32 + c * 8) : (CI + cb * 32 + (c - 4) * 8);
        v = *(const float4*)(actIn + ((long)img * H * H + gy * H + gx) * PIX_IN + coff);
      }
      *(float4*)(smem + c * PLSTR + px * 8) = v;
    }
    __syncthreads();

    for (int s = 0; s < 9; ++s) {
      const int ky = s / 3, kx = s - 3 * (s / 3);
      const long ub = ((long)(s * NCB + cb) * NF + blkco * (COB / 16) + cog * 4) * 1024
                      + lane * 8;
      short8 bh[4], bl[4];
      #pragma unroll
      for (int nf = 0; nf < 4; ++nf) {
        bh[nf] = *(const short8*)(wPk + ub + nf * 1024);
        bl[nf] = *(const short8*)(wPk + ub + nf * 1024 + 512);
      }
      #pragma unroll
      for (int mf = 0; mf < 4; ++mf) {
        const int y = pxg * ROWS_PG + mf;
        const int pxa = (y + ky) * PXW + kx + lx;
        short8 ah = *(const short8*)(smem + kg * PLSTR + pxa * 8);
        short8 al = *(const short8*)(smem + (kg + 4) * PLSTR + pxa * 8);
        #pragma unroll
        for (int nf = 0; nf < 4; ++nf)
          acc[mf][nf] = __builtin_amdgcn_mfma_f32_16x16x32_bf16(ah, bh[nf], acc[mf][nf], 0, 0, 0);
        #pragma unroll
        for (int nf = 0; nf < 4; ++nf)
          acc[mf][nf] = __builtin_amdgcn_mfma_f32_16x16x32_bf16(ah, bl[nf], acc[mf][nf], 0, 0, 0);
        #pragma unroll
        for (int nf = 0; nf < 4; ++nf)
          acc[mf][nf] = __builtin_amdgcn_mfma_f32_16x16x32_bf16(al, bh[nf], acc[mf][nf], 0, 0, 0);
      }
    }
  }

  float Ar[4], Cr[4];
  #pragma unroll
  for (int nf = 0; nf < 4; ++nf) {
    int co = blkco * COB + cog * 64 + nf * 16 + lx;
    Ar[nf] = Ap[co]; Cr[nf] = Cp[co];
  }

  // MODE 2: 2x2 maxpool + BN/ReLU + global average -> feats
  float psum[4] = {0.f, 0.f, 0.f, 0.f};
  #pragma unroll
  for (int nf = 0; nf < 4; ++nf) {
    #pragma unroll
    for (int mfp = 0; mfp < 2; ++mfp) {
      #pragma unroll
      for (int rp = 0; rp < 2; ++rp) {
        float v = fmaxf(fmaxf(acc[2 * mfp][nf][2 * rp], acc[2 * mfp][nf][2 * rp + 1]),
                        fmaxf(acc[2 * mfp + 1][nf][2 * rp], acc[2 * mfp + 1][nf][2 * rp + 1]));
        psum[nf] += fmaxf(v * Ar[nf] + Cr[nf], 0.f);
      }
    }
  }
  #pragma unroll
  for (int nf = 0; nf < 4; ++nf) {
    psum[nf] += __shfl_xor(psum[nf], 16);
    psum[nf] += __shfl_xor(psum[nf], 32);
  }
  __syncthreads();
  float* sR = (float*)smem;
  if (kg == 0) {
    #pragma unroll
    for (int nf = 0; nf < 4; ++nf) sR[w * 64 + nf * 16 + lx] = psum[nf];
  }
  __syncthreads();
  if (tid < COB) {
    int ct = tid >> 6, ci_ = tid & 63;
    float s = 0.f;
    #pragma unroll
    for (int p = 0; p < NPXG; ++p) s += sR[(ct * NPXG + p) * 64 + ci_];
    ((float*)outP)[(long)img * 256 + blkco * COB + tid] = s * (1.f / 64.f);
  }
}

// ---------------------------------------------------------------------------
// heads / sort / routing / combine (unchanged)
__global__ __launch_bounds__(256) void heads2_kernel(
    const float* __restrict__ feats, const float* __restrict__ gw1,
    const float* __restrict__ gb1, const float* __restrict__ gw2,
    const float* __restrict__ gb2, const float* __restrict__ clsw,
    const float* __restrict__ clsb, const float* __restrict__ usage,
    float* __restrict__ logits_e, float* __restrict__ rs_out)
{
  __shared__ float sF[64 * 257];
  __shared__ float sLg[4 * 64 * 10];
  __shared__ float sRed[4 * 64];
  const int tid = threadIdx.x;
  const int b0 = blockIdx.x * 64;
  const int e  = blockIdx.y;

  for (int idx = tid; idx < 64 * 64; idx += 256) {
    int t = idx >> 6, dg = idx & 63;
    float4 v = ((const float4*)(feats + (long)(b0 + t) * 256))[dg];
    float* p = sF + t * 257 + dg * 4;
    p[0] = v.x; p[1] = v.y; p[2] = v.z; p[3] = v.w;
  }
  __syncthreads();

  const int t  = tid & 63;
  const int hw = __builtin_amdgcn_readfirstlane(tid >> 6);

  {
    float acc[10];
    #pragma unroll
    for (int c = 0; c < 10; ++c) acc[c] = 0.f;
    const float* fp = sF + t * 257 + hw * 64;
    const float* cw = clsw + (long)e * 2560 + hw * 64;
    for (int dd = 0; dd < 64; ++dd) {
      float f = fp[dd];
      #pragma unroll
      for (int c = 0; c < 10; ++c) acc[c] += f * cw[c * 256 + dd];
    }
    #pragma unroll
    for (int c = 0; c < 10; ++c) sLg[(hw * 64 + t) * 10 + c] = acc[c];
  }
  {
    float gacc[32];
    #pragma unroll
    for (int j = 0; j < 32; ++j) gacc[j] = 0.f;
    const float* wb = gw1 + ((long)e * 256) * 128 + hw * 32;
    const float* fp = sF + t * 257;
    for (int d = 0; d < 256; ++d) {
      float f = fp[d];
      const float4* w4 = (const float4*)(wb + (long)d * 128);
      #pragma unroll
      for (int qq = 0; qq < 8; ++qq) {
        float4 wv = w4[qq];
        gacc[4 * qq + 0] += f * wv.x; gacc[4 * qq + 1] += f * wv.y;
        gacc[4 * qq + 2] += f * wv.z; gacc[4 * qq + 3] += f * wv.w;
      }
    }
    float s = 0.f;
    const float* b1 = gb1 + e * 128 + hw * 32;
    const float* w2 = gw2 + e * 128 + hw * 32;
    #pragma unroll
    for (int j = 0; j < 32; ++j) s += fmaxf(gacc[j] + b1[j], 0.f) * w2[j];
    sRed[hw * 64 + t] = s;
  }
  __syncthreads();

  if (tid < 64) {
    float es = (sRed[t] + sRed[64 + t] + sRed[128 + t] + sRed[192 + t] + gb2[e]) * 0.5f;
    float lg[10];
    #pragma unroll
    for (int c = 0; c < 10; ++c)
      lg[c] = sLg[t * 10 + c] + sLg[(64 + t) * 10 + c]
            + sLg[(128 + t) * 10 + c] + sLg[(192 + t) * 10 + c] + clsb[e * 10 + c];
    float mx = lg[0];
    #pragma unroll
    for (int c = 1; c < 10; ++c) mx = fmaxf(mx, lg[c]);
    float S = 0.f, ps[10];
    #pragma unroll
    for (int c = 0; c < 10; ++c) { ps[c] = expf(lg[c] - mx); S += ps[c]; }
    float inv = 1.f / S, ent = 0.f;
    #pragma unroll
    for (int c = 0; c < 10; ++c) { float p = ps[c] * inv; ent -= p * logf(fmaxf(p, 1e-12f)); }
    float rsv = 0.6f * es + 0.4f * (-ent) - 2.0f * usage[e];
    rs_out[(long)(b0 + t) * 16 + e] = rsv;
    #pragma unroll
    for (int c = 0; c < 10; ++c)
      logits_e[((long)(b0 + t) * 16 + e) * 10 + c] = lg[c];
  }
}

__global__ __launch_bounds__(1024) void sort_kernel(
    const float* __restrict__ rs, unsigned* __restrict__ sortedIdx)
{
  __shared__ unsigned long long sk[2048];
  const int e = blockIdx.x;
  const unsigned tid = threadIdx.x;
  for (int i = tid; i < 2048; i += 1024) {
    float f = rs[(long)i * 16 + e];
    unsigned u = __float_as_uint(f);
    u ^= (u >> 31) ? 0xFFFFFFFFu : 0x80000000u;
    sk[i] = ((unsigned long long)(~u) << 32) | (unsigned)i;
  }
  for (unsigned k = 2; k <= 2048; k <<= 1) {
    for (unsigned j = k >> 1; j > 0; j >>= 1) {
      __syncthreads();
      unsigned i = ((tid & ~(j - 1)) << 1) | (tid & (j - 1));
      unsigned p = i | j;
      bool asc = ((i & k) == 0);
      unsigned long long a = sk[i], b = sk[p];
      if ((a > b) == asc) { sk[i] = b; sk[p] = a; }
    }
  }
  __syncthreads();
  for (int i = tid; i < 2048; i += 1024)
    sortedIdx[(long)e * 2048 + i] = (unsigned)(sk[i] & 0xFFFFFFFFull);
}

__global__ __launch_bounds__(1024) void routing_kernel(
    const unsigned* __restrict__ sortedIdx, const float* __restrict__ rs,
    float* __restrict__ Dout, unsigned* __restrict__ dmaskOut)
{
  __shared__ unsigned char sAvail[2048];
  __shared__ unsigned sDm[2048];
  __shared__ int sLoads[16];
  __shared__ int sWaveCnt[16];
  __shared__ int sNtc, sVC;
  const int tid = threadIdx.x;
  const int lane = tid & 63, wave = tid >> 6;
  for (int i = tid; i < 2048; i += 1024) { sAvail[i] = 1; sDm[i] = 0; }
  if (tid < 16) sLoads[tid] = 0;
  if (tid == 0) sVC = 2048;
  __syncthreads();
  for (int it = 0; it < 3; ++it) {
    for (int j = 0; j < 16; ++j) {
      if (tid == 0) {
        int rc = 256 - sLoads[j]; if (rc < 0) rc = 0;
        int vc = sVC, ntc = 0;
        if (rc > 0 && vc > 0) {
          int a = rc < vc ? rc : vc;
          int b2 = vc < 102 ? vc : 102;
          ntc = a > b2 ? a : b2;
        }
        sNtc = ntc; sLoads[j] += ntc; sVC -= ntc;
      }
      __syncthreads();
      const int ntc = sNtc;
      if (ntc > 0) {
        int base = 0;
        for (int p = 0; p < 2; ++p) {
          int i = p * 1024 + tid;
          unsigned tok = sortedIdx[(long)j * 2048 + i];
          int fl = sAvail[tok] ? 1 : 0;
          unsigned long long bm = __ballot(fl);
          if (lane == 0) sWaveCnt[wave] = __popcll(bm);
          __syncthreads();
          int off = base;
          for (int w = 0; w < wave; ++w) off += sWaveCnt[w];
          int pre = off + __popcll(bm & ((1ull << lane) - 1ull));
          if (fl && pre < ntc) { sAvail[tok] = 0; sDm[tok] |= (1u << j); }
          int tot = base;
          for (int w = 0; w < 16; ++w) tot += sWaveCnt[w];
          base = tot;
          __syncthreads();
        }
      }
      __syncthreads();
    }
  }
  if (tid == 0 && sVC > 0) {
    for (int i = 0; i < 2048; ++i) {
      if (!sAvail[i]) continue;
      float s0 = -3.4e38f, s1 = s0, s2 = s0; int e0 = 0, e1 = 0, e2 = 0;
      for (int e = 0; e < 16; ++e) {
        float s = rs[i * 16 + e];
        if (s > s0)      { s2 = s1; e2 = e1; s1 = s0; e1 = e0; s0 = s; e0 = e; }
        else if (s > s1) { s2 = s1; e2 = e1; s1 = s;  e1 = e; }
        else if (s > s2) { s2 = s;  e2 = e; }
      }
      int best = e0, bl = sLoads[e0];
      if (sLoads[e1] < bl) { best = e1; bl = sLoads[e1]; }
      if (sLoads[e2] < bl) { best = e2; bl = sLoads[e2]; }
      sDm[i] |= (1u << best);
      sLoads[best] += 1;
    }
  }
  __syncthreads();
  for (int idx = tid; idx < 2048 * 16; idx += 1024) {
    int tok = idx >> 4, e = idx & 15;
    Dout[idx] = ((sDm[tok] >> e) & 1u) ? 1.0f : 0.0f;
  }
  for (int i = tid; i < 2048; i += 1024) dmaskOut[i] = sDm[i];
}

__global__ __launch_bounds__(256) void combine_kernel(
    const unsigned* __restrict__ dmask, const float* __restrict__ rs,
    const float* __restrict__ L, float* __restrict__ out)
{
  int i = blockIdx.x * 256 + threadIdx.x;
  if (i >= 2048) return;
  unsigned dm = dmask[i];
  float r[16];
  #pragma unroll
  for (int e = 0; e < 16; ++e) r[e] = rs[i * 16 + e];
  float mx = -3.4e38f;
  #pragma unroll
  for (int e = 0; e < 16; ++e) {
    float v = ((dm >> e) & 1u) ? r[e] : 0.0f;
    mx = fmaxf(mx, v);
  }
  float w[16], S = 0.f;
  #pragma unroll
  for (int e = 0; e < 16; ++e) {
    w[e] = ((dm >> e) & 1u) ? expf(r[e] - mx) : 0.0f;
    S += w[e];
  }
  float inv = 1.f / S;
  #pragma unroll
  for (int c = 0; c < 10; ++c) {
    float a = 0.f;
    #pragma unroll
    for (int e = 0; e < 16; ++e) a += w[e] * L[((long)i * 16 + e) * 10 + c];
    out[i * 10 + c] = a * inv;
  }
}

// ---------------------------------------------------------------------------
extern "C" void kernel_launch(void* const* d_in, const int* in_sizes, int n_in,
                              void* d_out, int out_size, void* d_ws, size_t ws_size,
                              hipStream_t stream)
{
  const float* x    = (const float*)d_in[0];
  const float* cw1  = (const float*)d_in[1];
  const float* cb1  = (const float*)d_in[2];
  const float* g1   = (const float*)d_in[3];
  const float* be1  = (const float*)d_in[4];
  const float* m1   = (const float*)d_in[5];
  const float* v1   = (const float*)d_in[6];
  const float* cw2  = (const float*)d_in[7];
  const float* cb2  = (const float*)d_in[8];
  const float* g2   = (const float*)d_in[9];
  const float* be2  = (const float*)d_in[10];
  const float* m2   = (const float*)d_in[11];
  const float* v2   = (const float*)d_in[12];
  const float* cw3  = (const float*)d_in[13];
  const float* cb3  = (const float*)d_in[14];
  const float* g3   = (const float*)d_in[15];
  const float* be3  = (const float*)d_in[16];
  const float* m3   = (const float*)d_in[17];
  const float* v3   = (const float*)d_in[18];
  const float* cw4  = (const float*)d_in[19];
  const float* cb4  = (const float*)d_in[20];
  const float* g4   = (const float*)d_in[21];
  const float* be4  = (const float*)d_in[22];
  const float* m4   = (const float*)d_in[23];
  const float* v4   = (const float*)d_in[24];
  const float* gw1  = (const float*)d_in[25];
  const float* gb1  = (const float*)d_in[26];
  const float* gw2  = (const float*)d_in[27];
  const float* gb2  = (const float*)d_in[28];
  const float* clsw = (const float*)d_in[29];
  const float* clsb = (const float*)d_in[30];
  const float* usage = (const float*)d_in[31];

  float* out = (float*)d_out;
  float* ws  = (float*)d_ws;

  float* A1 = ws + 0;   float* C1 = ws + 32;
  float* A2 = ws + 64;  float* C2 = ws + 128;
  float* A3 = ws + 192; float* C3 = ws + 320;
  float* A4 = ws + 448; float* C4 = ws + 704;
  float* feats   = ws + 1024;                       // 2048*256
  float* logitsE = ws + 525312;                     // 2048*16*10
  unsigned* sortedIdx = (unsigned*)(ws + 852992);   // 16*2048
  unsigned* dmask     = (unsigned*)(ws + 885760);   // 2048
  unsigned short* wPk2 = (unsigned short*)(ws + 887808);   // 36 units  * 1024 halves
  unsigned short* wPk3 = (unsigned short*)(ws + 906240);   // 144 units * 1024
  unsigned short* wPk4 = (unsigned short*)(ws + 979968);   // 576 units * 1024
  const long bufBase = 1274880;

  long wsFloats = (long)(ws_size / 4);
  long availF = wsFloats - bufBase;
  long chunkL = availF / 49152;   // per-img: bufA 32768 f + bufB 16384 f
  int chunk = (int)(chunkL < 1 ? 1 : (chunkL > 2048 ? 2048 : chunkL));

  bnprep_kernel<<<1, 256, 0, stream>>>(g1, be1, m1, v1, cb1, A1, C1, 32);
  bnprep_kernel<<<1, 256, 0, stream>>>(g2, be2, m2, v2, cb2, A2, C2, 64);
  bnprep_kernel<<<1, 256, 0, stream>>>(g3, be3, m3, v3, cb3, A3, C3, 128);
  bnprep_kernel<<<1, 256, 0, stream>>>(g4, be4, m4, v4, cb4, A4, C4, 256);
  wprep2_kernel<<<(2304 + 255) / 256, 256, 0, stream>>>(cw2, wPk2, 64, 32);
  wprep2_kernel<<<(9216 + 255) / 256, 256, 0, stream>>>(cw3, wPk3, 128, 64);
  wprep2_kernel<<<(36864 + 255) / 256, 256, 0, stream>>>(cw4, wPk4, 256, 128);

  unsigned short* bufA = (unsigned short*)(ws + bufBase);
  unsigned short* bufB = bufA + (long)chunk * 65536;

  for (int ib = 0; ib < 2048; ib += chunk) {
    int n = 2048 - ib; if (n > chunk) n = chunk;
    conv1_kernel<<<dim3(n, 4), 256, 0, stream>>>(x + (long)ib * 3072, cw1, A1, C1, bufA);
    // conv2: 32x32, 32->64ch, fused maxpool -> act2 (16x16, [hi64|lo64])
    convmf2_kernel<32, 32, 64, 1>
        <<<dim3(n * 4), 256, 0, stream>>>(bufA, wPk2, A2, C2, bufB);
    // conv3: 16x16, 64->128ch, plain store -> act3
    convmf2_kernel<16, 64, 128, 0>
        <<<dim3(n * 2), 256, 0, stream>>>(bufB, wPk3, A3, C3, bufA);
    // conv4: 16x16, 128->256ch, 512-thr 8-wave, 2 co-blocks/img, pool+avg
    convmf3_kernel<16, 128, 256, 128, 16, 16, 2>
        <<<dim3(n * 2), 512, 0, stream>>>(bufA, wPk4, A4, C4, feats + (long)ib * 256);
  }

  float* rsOut = out + 20480;
  heads2_kernel<<<dim3(32, 16), 256, 0, stream>>>(feats, gw1, gb1, gw2, gb2,
                                                  clsw, clsb, usage, logitsE, rsOut);
  sort_kernel<<<16, 1024, 0, stream>>>(rsOut, sortedIdx);
  routing_kernel<<<1, 1024, 0, stream>>>(sortedIdx, rsOut, out + 53248, dmask);
  combine_kernel<<<8, 256, 0, stream>>>(dmask, rsOut, logitsE, out);
}

// Round 7
// 1602.799 us; speedup vs baseline: 2.5736x; 2.0537x over previous
//
#include <hip/hip_runtime.h>

typedef __attribute__((ext_vector_type(8))) short short8;
typedef __attribute__((ext_vector_type(4))) float f32x4;

__device__ __forceinline__ unsigned short f2bf(float f) {
  unsigned u = __float_as_uint(f);
  unsigned r = (u + 0x7fffu + ((u >> 16) & 1u)) >> 16;
  return (unsigned short)r;
}
__device__ __forceinline__ float bf2f(unsigned short h) {
  return __uint_as_float(((unsigned)h) << 16);
}

// ---------------------------------------------------------------------------
__global__ __launch_bounds__(256) void bnprep_kernel(
    const float* __restrict__ g, const float* __restrict__ be,
    const float* __restrict__ m, const float* __restrict__ v,
    const float* __restrict__ b, float* __restrict__ A, float* __restrict__ C, int n)
{
  int i = blockIdx.x * 256 + threadIdx.x;
  if (i < n) {
    float s = g[i] / sqrtf(v[i] + 1e-5f);
    A[i] = s;
    C[i] = (b[i] - m[i]) * s + be[i];
  }
}

// Pre-pack conv weights into MFMA B-fragment order:
// unit = (s*NCB + cb)*NF + f ; halves addr = unit*1024 + plane*512 + lane*8 + j
__global__ __launch_bounds__(256) void wprep2_kernel(
    const float* __restrict__ w, unsigned short* __restrict__ wPk, int CO, int CI)
{
  int NCB = CI / 32, NF = CO / 16;
  int total = 9 * NCB * NF * 64;
  int idx = blockIdx.x * 256 + threadIdx.x;
  if (idx >= total) return;
  int lane = idx & 63;
  int unit = idx >> 6;
  int f = unit % NF;
  int cb = (unit / NF) % NCB;
  int s = unit / (NF * NCB);
  int co = f * 16 + (lane & 15);
  int ci0 = cb * 32 + (lane >> 4) * 8;
  long base = (long)unit * 1024 + lane * 8;
  #pragma unroll
  for (int j = 0; j < 8; ++j) {
    float v = w[((long)co * CI + ci0 + j) * 9 + s];
    unsigned short h = f2bf(v);
    unsigned short l = f2bf(v - bf2f(h));
    wPk[base + j] = h;
    wPk[base + 512 + j] = l;
  }
}

// conv1: 3->32, 32x32, fp32 compute, emits channel-last split-bf16.
__global__ __launch_bounds__(256) void conv1_kernel(
    const float* __restrict__ in, const float* __restrict__ wgt,
    const float* __restrict__ Ap, const float* __restrict__ Cp,
    unsigned short* __restrict__ out)
{
  __shared__ alignas(16) float smem[3 * 432 + 864];
  const int tid = threadIdx.x;
  const int img = blockIdx.x;
  const int by = (blockIdx.y >> 1) * 16, bx = (blockIdx.y & 1) * 16;
  const int r0 = (tid & 63) >> 4, xx = tid & 15, cog = tid >> 6;

  float acc[4][8];
  #pragma unroll
  for (int i = 0; i < 4; ++i)
    #pragma unroll
    for (int j = 0; j < 8; ++j) acc[i][j] = 0.f;

  for (int e = tid; e < 972; e += 256) {
    int ci = e / 324, rem = e - ci * 324;
    int rr = rem / 18, cc = rem - rr * 18;
    int gy = by + rr - 1, gx = bx + cc - 1;
    float v = 0.f;
    if (gy >= 0 && gy < 32 && gx >= 0 && gx < 32)
      v = in[(long)img * 3072 + ci * 1024 + gy * 32 + gx];
    smem[ci * 432 + rr * 24 + cc] = v;
  }
  for (int e = tid; e < 864; e += 256) {
    int co = e & 31, rem = e >> 5;
    smem[1296 + rem * 32 + co] = wgt[(long)co * 27 + rem];
  }
  __syncthreads();
  for (int ci = 0; ci < 3; ++ci) {
    #pragma unroll
    for (int k = 0; k < 9; ++k) {
      int ky = k / 3, kx = k - 3 * (k / 3);
      const float4* w4 = (const float4*)(smem + 1296 + (ci * 9 + k) * 32 + cog * 8);
      float4 w0 = w4[0], w1 = w4[1];
      #pragma unroll
      for (int i = 0; i < 4; ++i) {
        float iv = smem[ci * 432 + (r0 + 4 * i + ky) * 24 + xx + kx];
        acc[i][0] += iv * w0.x; acc[i][1] += iv * w0.y;
        acc[i][2] += iv * w0.z; acc[i][3] += iv * w0.w;
        acc[i][4] += iv * w1.x; acc[i][5] += iv * w1.y;
        acc[i][6] += iv * w1.z; acc[i][7] += iv * w1.w;
      }
    }
  }
  #pragma unroll
  for (int j = 0; j < 8; ++j) {
    int co = cog * 8 + j;
    float Ar = Ap[co], Cr = Cp[co];
    #pragma unroll
    for (int i = 0; i < 4; ++i) {
      float vv = fmaxf(acc[i][j] * Ar + Cr, 0.f);
      unsigned short h = f2bf(vv);
      unsigned short l = f2bf(vv - bf2f(h));
      long px = (long)img * 1024 + (by + r0 + 4 * i) * 32 + bx + xx;
      out[px * 64 + co] = h;
      out[px * 64 + 32 + co] = l;
    }
  }
}

// ---------------------------------------------------------------------------
// Split-bf16 MFMA conv (round-4 proven): 256 thr / 4 waves, 64 co per block.
// A tile in LDS, B fragments from global, LDS-transpose coalesced epilogue.
template<int H, int CI, int CO, int MODE>
__global__ __launch_bounds__(256, 3) void convmf2_kernel(
    const unsigned short* __restrict__ actIn, const unsigned short* __restrict__ wPk,
    const float* __restrict__ Ap, const float* __restrict__ Cp,
    void* __restrict__ outP)
{
  constexpr int NCB = CI / 32;
  constexpr int TILES = (H == 32) ? 4 : 1;
  constexpr int COGN = CO / 64;
  constexpr int TPI = TILES * COGN;
  constexpr int PIX_IN = 2 * CI;
  constexpr int NF = CO / 16;
  __shared__ alignas(16) unsigned short smem[23328];   // 324 x 72 halves

  const int nwg = gridDim.x;
  const int orig = blockIdx.x;
  const int q = nwg >> 3, r = nwg & 7;
  const int xcd = orig & 7, pos = orig >> 3;
  const int bx = (xcd < r ? xcd * (q + 1) : r * (q + 1) + (xcd - r) * q) + pos;

  const int img = bx / TPI;
  const int sub = bx % TPI;
  const int tY0 = (H == 32) ? ((sub >> 1) & 1) * 16 : 0;
  const int tX0 = (H == 32) ? (sub & 1) * 16 : 0;
  const int coG = (H == 32) ? 0 : sub;

  const int tid = threadIdx.x;
  const int lane = tid & 63;
  const int lx = lane & 15;
  const int kg = lane >> 4;
  const int w = tid >> 6;

  f32x4 acc[4][4];
  #pragma unroll
  for (int i = 0; i < 4; ++i)
    #pragma unroll
    for (int j = 0; j < 4; ++j) acc[i][j] = (f32x4){0.f, 0.f, 0.f, 0.f};

  for (int cb = 0; cb < NCB; ++cb) {
    if (cb) __syncthreads();
    for (int t2 = tid; t2 < 2592; t2 += 256) {
      int lp = t2 >> 3, c = t2 & 7;
      int ry = lp / 18, rx = lp - ry * 18;
      int gy = tY0 + ry - 1, gx = tX0 + rx - 1;
      float4 v = (float4){0.f, 0.f, 0.f, 0.f};
      if (gy >= 0 && gy < H && gx >= 0 && gx < H) {
        int coff = (c < 4) ? (cb * 32 + c * 8) : (CI + cb * 32 + (c - 4) * 8);
        v = *(const float4*)(actIn + ((long)img * H * H + gy * H + gx) * PIX_IN + coff);
      }
      *(float4*)(smem + lp * 72 + c * 8) = v;
    }
    __syncthreads();

    for (int s = 0; s < 9; ++s) {
      const int ky = s / 3, kx = s - 3 * (s / 3);
      const long ub = ((long)(s * NCB + cb) * NF + coG * 4) * 1024 + lane * 8;
      short8 bh[4], bl[4];
      #pragma unroll
      for (int nf = 0; nf < 4; ++nf) {
        bh[nf] = *(const short8*)(wPk + ub + nf * 1024);
        bl[nf] = *(const short8*)(wPk + ub + nf * 1024 + 512);
      }
      #pragma unroll
      for (int mf = 0; mf < 4; ++mf) {
        const unsigned short* ap = smem + ((w * 4 + mf + ky) * 18 + lx + kx) * 72 + kg * 8;
        short8 ah = *(const short8*)ap;
        short8 al = *(const short8*)(ap + 32);
        #pragma unroll
        for (int nf = 0; nf < 4; ++nf)
          acc[mf][nf] = __builtin_amdgcn_mfma_f32_16x16x32_bf16(ah, bh[nf], acc[mf][nf], 0, 0, 0);
        #pragma unroll
        for (int nf = 0; nf < 4; ++nf)
          acc[mf][nf] = __builtin_amdgcn_mfma_f32_16x16x32_bf16(ah, bl[nf], acc[mf][nf], 0, 0, 0);
        #pragma unroll
        for (int nf = 0; nf < 4; ++nf)
          acc[mf][nf] = __builtin_amdgcn_mfma_f32_16x16x32_bf16(al, bh[nf], acc[mf][nf], 0, 0, 0);
      }
    }
  }
  __syncthreads();   // A region now reusable as epilogue staging

  float ArV[4], CrV[4];
  #pragma unroll
  for (int nf = 0; nf < 4; ++nf) {
    int co = coG * 64 + nf * 16 + lx;
    ArV[nf] = Ap[co]; CrV[nf] = Cp[co];
  }

  if (MODE == 0) {
    unsigned short* outA = (unsigned short*)outP;
    unsigned short* slice = smem + w * 2048;
    #pragma unroll
    for (int mf = 0; mf < 4; ++mf) {
      int y = w * 4 + mf;
      #pragma unroll
      for (int rr = 0; rr < 4; ++rr) {
        int x = 4 * kg + rr;
        #pragma unroll
        for (int nf = 0; nf < 4; ++nf) {
          float vv = fmaxf(acc[mf][nf][rr] * ArV[nf] + CrV[nf], 0.f);
          unsigned short h = f2bf(vv);
          unsigned short l = f2bf(vv - bf2f(h));
          slice[(x * 2 + 0) * 64 + nf * 16 + lx] = h;
          slice[(x * 2 + 1) * 64 + nf * 16 + lx] = l;
        }
      }
      #pragma unroll
      for (int v = 0; v < 4; ++v) {
        int hoff = lane * 8 + v * 512;
        int x = hoff >> 7, rem = hoff & 127;
        int seg = rem >> 6, inner = rem & 63;
        short8 d = *(const short8*)(slice + hoff);
        *(short8*)(outA + ((long)img * 256 + y * 16 + x) * (2 * CO)
                   + seg * CO + coG * 64 + inner) = d;
      }
    }
  } else if (MODE == 1) {
    unsigned short* outA = (unsigned short*)outP;
    unsigned short* slice = smem + w * 1024;
    #pragma unroll
    for (int mfp = 0; mfp < 2; ++mfp) {
      int oy = (tY0 >> 1) + w * 2 + mfp;
      #pragma unroll
      for (int rp = 0; rp < 2; ++rp) {
        int oxl = 2 * kg + rp;
        #pragma unroll
        for (int nf = 0; nf < 4; ++nf) {
          float v0 = fmaxf(fmaxf(acc[2 * mfp][nf][2 * rp], acc[2 * mfp][nf][2 * rp + 1]),
                           fmaxf(acc[2 * mfp + 1][nf][2 * rp], acc[2 * mfp + 1][nf][2 * rp + 1]));
          float vv = fmaxf(v0 * ArV[nf] + CrV[nf], 0.f);
          unsigned short h = f2bf(vv);
          unsigned short l = f2bf(vv - bf2f(h));
          slice[(oxl * 2 + 0) * 64 + nf * 16 + lx] = h;
          slice[(oxl * 2 + 1) * 64 + nf * 16 + lx] = l;
        }
      }
      #pragma unroll
      for (int v = 0; v < 2; ++v) {
        int hoff = lane * 8 + v * 512;
        int oxl = hoff >> 7, rem = hoff & 127;
        int seg = rem >> 6, inner = rem & 63;
        short8 d = *(const short8*)(slice + hoff);
        *(short8*)(outA + ((long)img * 256 + oy * 16 + (tX0 >> 1) + oxl) * 128
                   + seg * 64 + inner) = d;
      }
    }
  } else {
    float psum[4] = {0.f, 0.f, 0.f, 0.f};
    #pragma unroll
    for (int nf = 0; nf < 4; ++nf) {
      #pragma unroll
      for (int mfp = 0; mfp < 2; ++mfp) {
        #pragma unroll
        for (int rp = 0; rp < 2; ++rp) {
          float v = fmaxf(fmaxf(acc[2 * mfp][nf][2 * rp], acc[2 * mfp][nf][2 * rp + 1]),
                          fmaxf(acc[2 * mfp + 1][nf][2 * rp], acc[2 * mfp + 1][nf][2 * rp + 1]));
          psum[nf] += fmaxf(v * ArV[nf] + CrV[nf], 0.f);
        }
      }
    }
    #pragma unroll
    for (int nf = 0; nf < 4; ++nf) {
      psum[nf] += __shfl_xor(psum[nf], 16);
      psum[nf] += __shfl_xor(psum[nf], 32);
    }
    __syncthreads();
    float* sR = (float*)smem;
    if (kg == 0) {
      #pragma unroll
      for (int nf = 0; nf < 4; ++nf) sR[w * 64 + nf * 16 + lx] = psum[nf];
    }
    __syncthreads();
    if (tid < 64) {
      float s = sR[tid] + sR[64 + tid] + sR[128 + tid] + sR[192 + tid];
      ((float*)outP)[(long)img * 256 + coG * 64 + tid] = s * (1.f / 64.f);
    }
  }
}

// ---------------------------------------------------------------------------
// conv4-only: 512-thr / 8-wave (4 px-groups x 2 co-groups), COB=128 -> 2
// blocks/img (halved A re-fetch). MODE 2 only: no global stores (pool+avg).
// __launch_bounds__(512, 2): 128-VGPR cap (kernel needs ~115) -- (512,4)
// capped at 64 VGPR and spilled ~6 GB/dispatch to scratch (round 5/6 bug).
template<int H, int CI, int CO, int COB, int TY, int TX, int MODE>
__global__ __launch_bounds__(512, 2) void convmf3_kernel(
    const unsigned short* __restrict__ actIn, const unsigned short* __restrict__ wPk,
    const float* __restrict__ Ap, const float* __restrict__ Cp,
    void* __restrict__ outP)
{
  constexpr int NCB = CI / 32;
  constexpr int NF  = CO / 16;
  constexpr int NCOG = COB / 64;
  constexpr int NPXG = 8 / NCOG;
  constexpr int ROWS_PG = TY / NPXG;
  constexpr int PXW = TX + 2;
  constexpr int PXT = (TY + 2) * PXW;
  constexpr int PLSTR = PXT * 8 + 8;
  constexpr int TILES_Y = H / TY;
  constexpr int CBLK = CO / COB;
  constexpr int TPI = TILES_Y * CBLK;
  constexpr int PIX_IN = 2 * CI;
  __shared__ alignas(16) unsigned short smem[8 * PLSTR];

  const int nwg = gridDim.x;
  const int orig = blockIdx.x;
  const int q = nwg >> 3, r = nwg & 7;
  const int xcd = orig & 7, pos = orig >> 3;
  const int bx = (xcd < r ? xcd * (q + 1) : r * (q + 1) + (xcd - r) * q) + pos;

  const int img = bx / TPI;
  const int sub = bx % TPI;
  const int tY0 = (sub % TILES_Y) * TY;
  const int blkco = sub / TILES_Y;

  const int tid = threadIdx.x;
  const int lane = tid & 63;
  const int lx = lane & 15, kg = lane >> 4;
  const int w = tid >> 6;
  const int pxg = w % NPXG, cog = w / NPXG;

  f32x4 acc[4][4];
  #pragma unroll
  for (int i = 0; i < 4; ++i)
    #pragma unroll
    for (int j = 0; j < 4; ++j) acc[i][j] = (f32x4){0.f, 0.f, 0.f, 0.f};

  for (int cb = 0; cb < NCB; ++cb) {
    if (cb) __syncthreads();
    for (int t2 = tid; t2 < PXT * 8; t2 += 512) {
      int px = t2 >> 3, c = t2 & 7;
      int ry = px / PXW, rx = px - ry * PXW;
      int gy = tY0 + ry - 1, gx = rx - 1;
      float4 v = (float4){0.f, 0.f, 0.f, 0.f};
      if (gy >= 0 && gy < H && gx >= 0 && gx < H) {
        int coff = (c < 4) ? (cb * 32 + c * 8) : (CI + cb * 32 + (c - 4) * 8);
        v = *(const float4*)(actIn + ((long)img * H * H + gy * H + gx) * PIX_IN + coff);
      }
      *(float4*)(smem + c * PLSTR + px * 8) = v;
    }
    __syncthreads();

    for (int s = 0; s < 9; ++s) {
      const int ky = s / 3, kx = s - 3 * (s / 3);
      const long ub = ((long)(s * NCB + cb) * NF + blkco * (COB / 16) + cog * 4) * 1024
                      + lane * 8;
      short8 bh[4], bl[4];
      #pragma unroll
      for (int nf = 0; nf < 4; ++nf) {
        bh[nf] = *(const short8*)(wPk + ub + nf * 1024);
        bl[nf] = *(const short8*)(wPk + ub + nf * 1024 + 512);
      }
      #pragma unroll
      for (int mf = 0; mf < 4; ++mf) {
        const int y = pxg * ROWS_PG + mf;
        const int pxa = (y + ky) * PXW + kx + lx;
        short8 ah = *(const short8*)(smem + kg * PLSTR + pxa * 8);
        short8 al = *(const short8*)(smem + (kg + 4) * PLSTR + pxa * 8);
        #pragma unroll
        for (int nf = 0; nf < 4; ++nf)
          acc[mf][nf] = __builtin_amdgcn_mfma_f32_16x16x32_bf16(ah, bh[nf], acc[mf][nf], 0, 0, 0);
        #pragma unroll
        for (int nf = 0; nf < 4; ++nf)
          acc[mf][nf] = __builtin_amdgcn_mfma_f32_16x16x32_bf16(ah, bl[nf], acc[mf][nf], 0, 0, 0);
        #pragma unroll
        for (int nf = 0; nf < 4; ++nf)
          acc[mf][nf] = __builtin_amdgcn_mfma_f32_16x16x32_bf16(al, bh[nf], acc[mf][nf], 0, 0, 0);
      }
    }
  }

  float Ar[4], Cr[4];
  #pragma unroll
  for (int nf = 0; nf < 4; ++nf) {
    int co = blkco * COB + cog * 64 + nf * 16 + lx;
    Ar[nf] = Ap[co]; Cr[nf] = Cp[co];
  }

  // MODE 2: 2x2 maxpool + BN/ReLU + global average -> feats
  float psum[4] = {0.f, 0.f, 0.f, 0.f};
  #pragma unroll
  for (int nf = 0; nf < 4; ++nf) {
    #pragma unroll
    for (int mfp = 0; mfp < 2; ++mfp) {
      #pragma unroll
      for (int rp = 0; rp < 2; ++rp) {
        float v = fmaxf(fmaxf(acc[2 * mfp][nf][2 * rp], acc[2 * mfp][nf][2 * rp + 1]),
                        fmaxf(acc[2 * mfp + 1][nf][2 * rp], acc[2 * mfp + 1][nf][2 * rp + 1]));
        psum[nf] += fmaxf(v * Ar[nf] + Cr[nf], 0.f);
      }
    }
  }
  #pragma unroll
  for (int nf = 0; nf < 4; ++nf) {
    psum[nf] += __shfl_xor(psum[nf], 16);
    psum[nf] += __shfl_xor(psum[nf], 32);
  }
  __syncthreads();
  float* sR = (float*)smem;
  if (kg == 0) {
    #pragma unroll
    for (int nf = 0; nf < 4; ++nf) sR[w * 64 + nf * 16 + lx] = psum[nf];
  }
  __syncthreads();
  if (tid < COB) {
    int ct = tid >> 6, ci_ = tid & 63;
    float s = 0.f;
    #pragma unroll
    for (int p = 0; p < NPXG; ++p) s += sR[(ct * NPXG + p) * 64 + ci_];
    ((float*)outP)[(long)img * 256 + blkco * COB + tid] = s * (1.f / 64.f);
  }
}

// ---------------------------------------------------------------------------
// heads / sort / routing / combine (unchanged)
__global__ __launch_bounds__(256) void heads2_kernel(
    const float* __restrict__ feats, const float* __restrict__ gw1,
    const float* __restrict__ gb1, const float* __restrict__ gw2,
    const float* __restrict__ gb2, const float* __restrict__ clsw,
    const float* __restrict__ clsb, const float* __restrict__ usage,
    float* __restrict__ logits_e, float* __restrict__ rs_out)
{
  __shared__ float sF[64 * 257];
  __shared__ float sLg[4 * 64 * 10];
  __shared__ float sRed[4 * 64];
  const int tid = threadIdx.x;
  const int b0 = blockIdx.x * 64;
  const int e  = blockIdx.y;

  for (int idx = tid; idx < 64 * 64; idx += 256) {
    int t = idx >> 6, dg = idx & 63;
    float4 v = ((const float4*)(feats + (long)(b0 + t) * 256))[dg];
    float* p = sF + t * 257 + dg * 4;
    p[0] = v.x; p[1] = v.y; p[2] = v.z; p[3] = v.w;
  }
  __syncthreads();

  const int t  = tid & 63;
  const int hw = __builtin_amdgcn_readfirstlane(tid >> 6);

  {
    float acc[10];
    #pragma unroll
    for (int c = 0; c < 10; ++c) acc[c] = 0.f;
    const float* fp = sF + t * 257 + hw * 64;
    const float* cw = clsw + (long)e * 2560 + hw * 64;
    for (int dd = 0; dd < 64; ++dd) {
      float f = fp[dd];
      #pragma unroll
      for (int c = 0; c < 10; ++c) acc[c] += f * cw[c * 256 + dd];
    }
    #pragma unroll
    for (int c = 0; c < 10; ++c) sLg[(hw * 64 + t) * 10 + c] = acc[c];
  }
  {
    float gacc[32];
    #pragma unroll
    for (int j = 0; j < 32; ++j) gacc[j] = 0.f;
    const float* wb = gw1 + ((long)e * 256) * 128 + hw * 32;
    const float* fp = sF + t * 257;
    for (int d = 0; d < 256; ++d) {
      float f = fp[d];
      const float4* w4 = (const float4*)(wb + (long)d * 128);
      #pragma unroll
      for (int qq = 0; qq < 8; ++qq) {
        float4 wv = w4[qq];
        gacc[4 * qq + 0] += f * wv.x; gacc[4 * qq + 1] += f * wv.y;
        gacc[4 * qq + 2] += f * wv.z; gacc[4 * qq + 3] += f * wv.w;
      }
    }
    float s = 0.f;
    const float* b1 = gb1 + e * 128 + hw * 32;
    const float* w2 = gw2 + e * 128 + hw * 32;
    #pragma unroll
    for (int j = 0; j < 32; ++j) s += fmaxf(gacc[j] + b1[j], 0.f) * w2[j];
    sRed[hw * 64 + t] = s;
  }
  __syncthreads();

  if (tid < 64) {
    float es = (sRed[t] + sRed[64 + t] + sRed[128 + t] + sRed[192 + t] + gb2[e]) * 0.5f;
    float lg[10];
    #pragma unroll
    for (int c = 0; c < 10; ++c)
      lg[c] = sLg[t * 10 + c] + sLg[(64 + t) * 10 + c]
            + sLg[(128 + t) * 10 + c] + sLg[(192 + t) * 10 + c] + clsb[e * 10 + c];
    float mx = lg[0];
    #pragma unroll
    for (int c = 1; c < 10; ++c) mx = fmaxf(mx, lg[c]);
    float S = 0.f, ps[10];
    #pragma unroll
    for (int c = 0; c < 10; ++c) { ps[c] = expf(lg[c] - mx); S += ps[c]; }
    float inv = 1.f / S, ent = 0.f;
    #pragma unroll
    for (int c = 0; c < 10; ++c) { float p = ps[c] * inv; ent -= p * logf(fmaxf(p, 1e-12f)); }
    float rsv = 0.6f * es + 0.4f * (-ent) - 2.0f * usage[e];
    rs_out[(long)(b0 + t) * 16 + e] = rsv;
    #pragma unroll
    for (int c = 0; c < 10; ++c)
      logits_e[((long)(b0 + t) * 16 + e) * 10 + c] = lg[c];
  }
}

__global__ __launch_bounds__(1024) void sort_kernel(
    const float* __restrict__ rs, unsigned* __restrict__ sortedIdx)
{
  __shared__ unsigned long long sk[2048];
  const int e = blockIdx.x;
  const unsigned tid = threadIdx.x;
  for (int i = tid; i < 2048; i += 1024) {
    float f = rs[(long)i * 16 + e];
    unsigned u = __float_as_uint(f);
    u ^= (u >> 31) ? 0xFFFFFFFFu : 0x80000000u;
    sk[i] = ((unsigned long long)(~u) << 32) | (unsigned)i;
  }
  for (unsigned k = 2; k <= 2048; k <<= 1) {
    for (unsigned j = k >> 1; j > 0; j >>= 1) {
      __syncthreads();
      unsigned i = ((tid & ~(j - 1)) << 1) | (tid & (j - 1));
      unsigned p = i | j;
      bool asc = ((i & k) == 0);
      unsigned long long a = sk[i], b = sk[p];
      if ((a > b) == asc) { sk[i] = b; sk[p] = a; }
    }
  }
  __syncthreads();
  for (int i = tid; i < 2048; i += 1024)
    sortedIdx[(long)e * 2048 + i] = (unsigned)(sk[i] & 0xFFFFFFFFull);
}

__global__ __launch_bounds__(1024) void routing_kernel(
    const unsigned* __restrict__ sortedIdx, const float* __restrict__ rs,
    float* __restrict__ Dout, unsigned* __restrict__ dmaskOut)
{
  __shared__ unsigned char sAvail[2048];
  __shared__ unsigned sDm[2048];
  __shared__ int sLoads[16];
  __shared__ int sWaveCnt[16];
  __shared__ int sNtc, sVC;
  const int tid = threadIdx.x;
  const int lane = tid & 63, wave = tid >> 6;
  for (int i = tid; i < 2048; i += 1024) { sAvail[i] = 1; sDm[i] = 0; }
  if (tid < 16) sLoads[tid] = 0;
  if (tid == 0) sVC = 2048;
  __syncthreads();
  for (int it = 0; it < 3; ++it) {
    for (int j = 0; j < 16; ++j) {
      if (tid == 0) {
        int rc = 256 - sLoads[j]; if (rc < 0) rc = 0;
        int vc = sVC, ntc = 0;
        if (rc > 0 && vc > 0) {
          int a = rc < vc ? rc : vc;
          int b2 = vc < 102 ? vc : 102;
          ntc = a > b2 ? a : b2;
        }
        sNtc = ntc; sLoads[j] += ntc; sVC -= ntc;
      }
      __syncthreads();
      const int ntc = sNtc;
      if (ntc > 0) {
        int base = 0;
        for (int p = 0; p < 2; ++p) {
          int i = p * 1024 + tid;
          unsigned tok = sortedIdx[(long)j * 2048 + i];
          int fl = sAvail[tok] ? 1 : 0;
          unsigned long long bm = __ballot(fl);
          if (lane == 0) sWaveCnt[wave] = __popcll(bm);
          __syncthreads();
          int off = base;
          for (int w = 0; w < wave; ++w) off += sWaveCnt[w];
          int pre = off + __popcll(bm & ((1ull << lane) - 1ull));
          if (fl && pre < ntc) { sAvail[tok] = 0; sDm[tok] |= (1u << j); }
          int tot = base;
          for (int w = 0; w < 16; ++w) tot += sWaveCnt[w];
          base = tot;
          __syncthreads();
        }
      }
      __syncthreads();
    }
  }
  if (tid == 0 && sVC > 0) {
    for (int i = 0; i < 2048; ++i) {
      if (!sAvail[i]) continue;
      float s0 = -3.4e38f, s1 = s0, s2 = s0; int e0 = 0, e1 = 0, e2 = 0;
      for (int e = 0; e < 16; ++e) {
        float s = rs[i * 16 + e];
        if (s > s0)      { s2 = s1; e2 = e1; s1 = s0; e1 = e0; s0 = s; e0 = e; }
        else if (s > s1) { s2 = s1; e2 = e1; s1 = s;  e1 = e; }
        else if (s > s2) { s2 = s;  e2 = e; }
      }
      int best = e0, bl = sLoads[e0];
      if (sLoads[e1] < bl) { best = e1; bl = sLoads[e1]; }
      if (sLoads[e2] < bl) { best = e2; bl = sLoads[e2]; }
      sDm[i] |= (1u << best);
      sLoads[best] += 1;
    }
  }
  __syncthreads();
  for (int idx = tid; idx < 2048 * 16; idx += 1024) {
    int tok = idx >> 4, e = idx & 15;
    Dout[idx] = ((sDm[tok] >> e) & 1u) ? 1.0f : 0.0f;
  }
  for (int i = tid; i < 2048; i += 1024) dmaskOut[i] = sDm[i];
}

__global__ __launch_bounds__(256) void combine_kernel(
    const unsigned* __restrict__ dmask, const float* __restrict__ rs,
    const float* __restrict__ L, float* __restrict__ out)
{
  int i = blockIdx.x * 256 + threadIdx.x;
  if (i >= 2048) return;
  unsigned dm = dmask[i];
  float r[16];
  #pragma unroll
  for (int e = 0; e < 16; ++e) r[e] = rs[i * 16 + e];
  float mx = -3.4e38f;
  #pragma unroll
  for (int e = 0; e < 16; ++e) {
    float v = ((dm >> e) & 1u) ? r[e] : 0.0f;
    mx = fmaxf(mx, v);
  }
  float w[16], S = 0.f;
  #pragma unroll
  for (int e = 0; e < 16; ++e) {
    w[e] = ((dm >> e) & 1u) ? expf(r[e] - mx) : 0.0f;
    S += w[e];
  }
  float inv = 1.f / S;
  #pragma unroll
  for (int c = 0; c < 10; ++c) {
    float a = 0.f;
    #pragma unroll
    for (int e = 0; e < 16; ++e) a += w[e] * L[((long)i * 16 + e) * 10 + c];
    out[i * 10 + c] = a * inv;
  }
}

// ---------------------------------------------------------------------------
extern "C" void kernel_launch(void* const* d_in, const int* in_sizes, int n_in,
                              void* d_out, int out_size, void* d_ws, size_t ws_size,
                              hipStream_t stream)
{
  const float* x    = (const float*)d_in[0];
  const float* cw1  = (const float*)d_in[1];
  const float* cb1  = (const float*)d_in[2];
  const float* g1   = (const float*)d_in[3];
  const float* be1  = (const float*)d_in[4];
  const float* m1   = (const float*)d_in[5];
  const float* v1   = (const float*)d_in[6];
  const float* cw2  = (const float*)d_in[7];
  const float* cb2  = (const float*)d_in[8];
  const float* g2   = (const float*)d_in[9];
  const float* be2  = (const float*)d_in[10];
  const float* m2   = (const float*)d_in[11];
  const float* v2   = (const float*)d_in[12];
  const float* cw3  = (const float*)d_in[13];
  const float* cb3  = (const float*)d_in[14];
  const float* g3   = (const float*)d_in[15];
  const float* be3  = (const float*)d_in[16];
  const float* m3   = (const float*)d_in[17];
  const float* v3   = (const float*)d_in[18];
  const float* cw4  = (const float*)d_in[19];
  const float* cb4  = (const float*)d_in[20];
  const float* g4   = (const float*)d_in[21];
  const float* be4  = (const float*)d_in[22];
  const float* m4   = (const float*)d_in[23];
  const float* v4   = (const float*)d_in[24];
  const float* gw1  = (const float*)d_in[25];
  const float* gb1  = (const float*)d_in[26];
  const float* gw2  = (const float*)d_in[27];
  const float* gb2  = (const float*)d_in[28];
  const float* clsw = (const float*)d_in[29];
  const float* clsb = (const float*)d_in[30];
  const float* usage = (const float*)d_in[31];

  float* out = (float*)d_out;
  float* ws  = (float*)d_ws;

  float* A1 = ws + 0;   float* C1 = ws + 32;
  float* A2 = ws + 64;  float* C2 = ws + 128;
  float* A3 = ws + 192; float* C3 = ws + 320;
  float* A4 = ws + 448; float* C4 = ws + 704;
  float* feats   = ws + 1024;                       // 2048*256
  float* logitsE = ws + 525312;                     // 2048*16*10
  unsigned* sortedIdx = (unsigned*)(ws + 852992);   // 16*2048
  unsigned* dmask     = (unsigned*)(ws + 885760);   // 2048
  unsigned short* wPk2 = (unsigned short*)(ws + 887808);   // 36 units  * 1024 halves
  unsigned short* wPk3 = (unsigned short*)(ws + 906240);   // 144 units * 1024
  unsigned short* wPk4 = (unsigned short*)(ws + 979968);   // 576 units * 1024
  const long bufBase = 1274880;

  long wsFloats = (long)(ws_size / 4);
  long availF = wsFloats - bufBase;
  long chunkL = availF / 49152;   // per-img: bufA 32768 f + bufB 16384 f
  int chunk = (int)(chunkL < 1 ? 1 : (chunkL > 2048 ? 2048 : chunkL));

  bnprep_kernel<<<1, 256, 0, stream>>>(g1, be1, m1, v1, cb1, A1, C1, 32);
  bnprep_kernel<<<1, 256, 0, stream>>>(g2, be2, m2, v2, cb2, A2, C2, 64);
  bnprep_kernel<<<1, 256, 0, stream>>>(g3, be3, m3, v3, cb3, A3, C3, 128);
  bnprep_kernel<<<1, 256, 0, stream>>>(g4, be4, m4, v4, cb4, A4, C4, 256);
  wprep2_kernel<<<(2304 + 255) / 256, 256, 0, stream>>>(cw2, wPk2, 64, 32);
  wprep2_kernel<<<(9216 + 255) / 256, 256, 0, stream>>>(cw3, wPk3, 128, 64);
  wprep2_kernel<<<(36864 + 255) / 256, 256, 0, stream>>>(cw4, wPk4, 256, 128);

  unsigned short* bufA = (unsigned short*)(ws + bufBase);
  unsigned short* bufB = bufA + (long)chunk * 65536;

  for (int ib = 0; ib < 2048; ib += chunk) {
    int n = 2048 - ib; if (n > chunk) n = chunk;
    conv1_kernel<<<dim3(n, 4), 256, 0, stream>>>(x + (long)ib * 3072, cw1, A1, C1, bufA);
    // conv2: 32x32, 32->64ch, fused maxpool -> act2 (16x16, [hi64|lo64])
    convmf2_kernel<32, 32, 64, 1>
        <<<dim3(n * 4), 256, 0, stream>>>(bufA, wPk2, A2, C2, bufB);
    // conv3: 16x16, 64->128ch, plain store -> act3
    convmf2_kernel<16, 64, 128, 0>
        <<<dim3(n * 2), 256, 0, stream>>>(bufB, wPk3, A3, C3, bufA);
    // conv4: 16x16, 128->256ch, 512-thr 8-wave, 2 co-blocks/img, pool+avg
    convmf3_kernel<16, 128, 256, 128, 16, 16, 2>
        <<<dim3(n * 2), 512, 0, stream>>>(bufA, wPk4, A4, C4, feats + (long)ib * 256);
  }

  float* rsOut = out + 20480;
  heads2_kernel<<<dim3(32, 16), 256, 0, stream>>>(feats, gw1, gb1, gw2, gb2,
                                                  clsw, clsb, usage, logitsE, rsOut);
  sort_kernel<<<16, 1024, 0, stream>>>(rsOut, sortedIdx);
  routing_kernel<<<1, 1024, 0, stream>>>(sortedIdx, rsOut, out + 53248, dmask);
  combine_kernel<<<8, 256, 0, stream>>>(dmask, rsOut, logitsE, out);
}

// Round 8
// 1413.303 us; speedup vs baseline: 2.9187x; 1.1341x over previous
//
#include <hip/hip_runtime.h>

typedef __attribute__((ext_vector_type(8))) short short8;
typedef __attribute__((ext_vector_type(4))) float f32x4;

__device__ __forceinline__ unsigned short f2bf(float f) {
  unsigned u = __float_as_uint(f);
  unsigned r = (u + 0x7fffu + ((u >> 16) & 1u)) >> 16;
  return (unsigned short)r;
}
__device__ __forceinline__ float bf2f(unsigned short h) {
  return __uint_as_float(((unsigned)h) << 16);
}

// ---------------------------------------------------------------------------
__global__ __launch_bounds__(256) void bnprep_kernel(
    const float* __restrict__ g, const float* __restrict__ be,
    const float* __restrict__ m, const float* __restrict__ v,
    const float* __restrict__ b, float* __restrict__ A, float* __restrict__ C, int n)
{
  int i = blockIdx.x * 256 + threadIdx.x;
  if (i < n) {
    float s = g[i] / sqrtf(v[i] + 1e-5f);
    A[i] = s;
    C[i] = (b[i] - m[i]) * s + be[i];
  }
}

// Pre-pack conv weights into MFMA B-fragment order:
// unit = (s*NCB + cb)*NF + f ; halves addr = unit*1024 + plane*512 + lane*8 + j
__global__ __launch_bounds__(256) void wprep2_kernel(
    const float* __restrict__ w, unsigned short* __restrict__ wPk, int CO, int CI)
{
  int NCB = CI / 32, NF = CO / 16;
  int total = 9 * NCB * NF * 64;
  int idx = blockIdx.x * 256 + threadIdx.x;
  if (idx >= total) return;
  int lane = idx & 63;
  int unit = idx >> 6;
  int f = unit % NF;
  int cb = (unit / NF) % NCB;
  int s = unit / (NF * NCB);
  int co = f * 16 + (lane & 15);
  int ci0 = cb * 32 + (lane >> 4) * 8;
  long base = (long)unit * 1024 + lane * 8;
  #pragma unroll
  for (int j = 0; j < 8; ++j) {
    float v = w[((long)co * CI + ci0 + j) * 9 + s];
    unsigned short h = f2bf(v);
    unsigned short l = f2bf(v - bf2f(h));
    wPk[base + j] = h;
    wPk[base + 512 + j] = l;
  }
}

// conv1: 3->32, 32x32, fp32 compute, emits channel-last split-bf16.
__global__ __launch_bounds__(256) void conv1_kernel(
    const float* __restrict__ in, const float* __restrict__ wgt,
    const float* __restrict__ Ap, const float* __restrict__ Cp,
    unsigned short* __restrict__ out)
{
  __shared__ alignas(16) float smem[3 * 432 + 864];
  const int tid = threadIdx.x;
  const int img = blockIdx.x;
  const int by = (blockIdx.y >> 1) * 16, bx = (blockIdx.y & 1) * 16;
  const int r0 = (tid & 63) >> 4, xx = tid & 15, cog = tid >> 6;

  float acc[4][8];
  #pragma unroll
  for (int i = 0; i < 4; ++i)
    #pragma unroll
    for (int j = 0; j < 8; ++j) acc[i][j] = 0.f;

  for (int e = tid; e < 972; e += 256) {
    int ci = e / 324, rem = e - ci * 324;
    int rr = rem / 18, cc = rem - rr * 18;
    int gy = by + rr - 1, gx = bx + cc - 1;
    float v = 0.f;
    if (gy >= 0 && gy < 32 && gx >= 0 && gx < 32)
      v = in[(long)img * 3072 + ci * 1024 + gy * 32 + gx];
    smem[ci * 432 + rr * 24 + cc] = v;
  }
  for (int e = tid; e < 864; e += 256) {
    int co = e & 31, rem = e >> 5;
    smem[1296 + rem * 32 + co] = wgt[(long)co * 27 + rem];
  }
  __syncthreads();
  for (int ci = 0; ci < 3; ++ci) {
    #pragma unroll
    for (int k = 0; k < 9; ++k) {
      int ky = k / 3, kx = k - 3 * (k / 3);
      const float4* w4 = (const float4*)(smem + 1296 + (ci * 9 + k) * 32 + cog * 8);
      float4 w0 = w4[0], w1 = w4[1];
      #pragma unroll
      for (int i = 0; i < 4; ++i) {
        float iv = smem[ci * 432 + (r0 + 4 * i + ky) * 24 + xx + kx];
        acc[i][0] += iv * w0.x; acc[i][1] += iv * w0.y;
        acc[i][2] += iv * w0.z; acc[i][3] += iv * w0.w;
        acc[i][4] += iv * w1.x; acc[i][5] += iv * w1.y;
        acc[i][6] += iv * w1.z; acc[i][7] += iv * w1.w;
      }
    }
  }
  #pragma unroll
  for (int j = 0; j < 8; ++j) {
    int co = cog * 8 + j;
    float Ar = Ap[co], Cr = Cp[co];
    #pragma unroll
    for (int i = 0; i < 4; ++i) {
      float vv = fmaxf(acc[i][j] * Ar + Cr, 0.f);
      unsigned short h = f2bf(vv);
      unsigned short l = f2bf(vv - bf2f(h));
      long px = (long)img * 1024 + (by + r0 + 4 * i) * 32 + bx + xx;
      out[px * 64 + co] = h;
      out[px * 64 + 32 + co] = l;
    }
  }
}

// ---------------------------------------------------------------------------
// Unified split-bf16 MFMA conv: 512-thr / 8-wave blocks (NPXG px-groups x
// NCOG co-groups), A tile in 8-plane LDS, B fragments from global
// (L1/L2-resident). Coalesced epilogues via per-wave LDS transpose slices.
// MODE 0: plain store; 1: fused 2x2 maxpool store; 2: pool + global avg.
// (512,2): 128-VGPR cap (needs ~110); (512,4) would cap 64 and spill.
template<int H, int CI, int CO, int COB, int TY, int TX, int MODE>
__global__ __launch_bounds__(512, 2) void convmf4_kernel(
    const unsigned short* __restrict__ actIn, const unsigned short* __restrict__ wPk,
    const float* __restrict__ Ap, const float* __restrict__ Cp,
    void* __restrict__ outP)
{
  constexpr int NCB = CI / 32;
  constexpr int NF  = CO / 16;
  constexpr int NCOG = COB / 64;
  constexpr int NPXG = 8 / NCOG;
  constexpr int ROWS_PG = TY / NPXG;
  constexpr int FRX = TX / 16;
  constexpr int PXW = TX + 2;
  constexpr int PXT = (TY + 2) * PXW;
  constexpr int PLSTR = PXT * 8 + 8;       // halves; +8 staggers plane banks
  constexpr int TILES_Y = H / TY;
  constexpr int CBLK = CO / COB;
  constexpr int TPI = TILES_Y * CBLK;
  constexpr int PIX_IN = 2 * CI;
  __shared__ alignas(16) unsigned short smem[8 * PLSTR];

  // bijective XCD-chunked swizzle: sibling blocks (same img) share an XCD L2
  const int nwg = gridDim.x;
  const int orig = blockIdx.x;
  const int q = nwg >> 3, r = nwg & 7;
  const int xcd = orig & 7, pos = orig >> 3;
  const int bx = (xcd < r ? xcd * (q + 1) : r * (q + 1) + (xcd - r) * q) + pos;

  const int img = bx / TPI;
  const int sub = bx % TPI;
  const int tY0 = (sub % TILES_Y) * TY;
  const int blkco = sub / TILES_Y;

  const int tid = threadIdx.x;
  const int lane = tid & 63;
  const int lx = lane & 15, kg = lane >> 4;
  const int w = tid >> 6;
  const int pxg = w % NPXG, cog = w / NPXG;

  f32x4 acc[4][4];
  #pragma unroll
  for (int i = 0; i < 4; ++i)
    #pragma unroll
    for (int j = 0; j < 4; ++j) acc[i][j] = (f32x4){0.f, 0.f, 0.f, 0.f};

  for (int cb = 0; cb < NCB; ++cb) {
    if (cb) __syncthreads();
    // stage A tile (halo, zero-padded) into 8 ci-planes
    for (int t2 = tid; t2 < PXT * 8; t2 += 512) {
      int px = t2 >> 3, c = t2 & 7;
      int ry = px / PXW, rx = px - ry * PXW;
      int gy = tY0 + ry - 1, gx = rx - 1;
      float4 v = (float4){0.f, 0.f, 0.f, 0.f};
      if (gy >= 0 && gy < H && gx >= 0 && gx < H) {
        int coff = (c < 4) ? (cb * 32 + c * 8) : (CI + cb * 32 + (c - 4) * 8);
        v = *(const float4*)(actIn + ((long)img * H * H + gy * H + gx) * PIX_IN + coff);
      }
      *(float4*)(smem + c * PLSTR + px * 8) = v;
    }
    __syncthreads();

    for (int s = 0; s < 9; ++s) {
      const int ky = s / 3, kx = s - 3 * (s / 3);
      const long ub = ((long)(s * NCB + cb) * NF + blkco * (COB / 16) + cog * 4) * 1024
                      + lane * 8;
      short8 bh[4], bl[4];
      #pragma unroll
      for (int nf = 0; nf < 4; ++nf) {
        bh[nf] = *(const short8*)(wPk + ub + nf * 1024);
        bl[nf] = *(const short8*)(wPk + ub + nf * 1024 + 512);
      }
      #pragma unroll
      for (int mf = 0; mf < 4; ++mf) {
        const int yoff = (FRX == 2) ? (mf >> 1) : mf;
        const int xb = (FRX == 2) ? ((mf & 1) * 16) : 0;
        const int y = pxg * ROWS_PG + yoff;
        const int pxa = (y + ky) * PXW + xb + kx + lx;
        short8 ah = *(const short8*)(smem + kg * PLSTR + pxa * 8);
        short8 al = *(const short8*)(smem + (kg + 4) * PLSTR + pxa * 8);
        #pragma unroll
        for (int nf = 0; nf < 4; ++nf)
          acc[mf][nf] = __builtin_amdgcn_mfma_f32_16x16x32_bf16(ah, bh[nf], acc[mf][nf], 0, 0, 0);
        #pragma unroll
        for (int nf = 0; nf < 4; ++nf)
          acc[mf][nf] = __builtin_amdgcn_mfma_f32_16x16x32_bf16(ah, bl[nf], acc[mf][nf], 0, 0, 0);
        #pragma unroll
        for (int nf = 0; nf < 4; ++nf)
          acc[mf][nf] = __builtin_amdgcn_mfma_f32_16x16x32_bf16(al, bh[nf], acc[mf][nf], 0, 0, 0);
      }
    }
  }
  __syncthreads();   // A region now reusable as epilogue staging

  float Ar[4], Cr[4];
  #pragma unroll
  for (int nf = 0; nf < 4; ++nf) {
    int co = blkco * COB + cog * 64 + nf * 16 + lx;
    Ar[nf] = Ap[co]; Cr[nf] = Cp[co];
  }

  if (MODE == 0) {
    // plain store via per-wave 4KB transpose slice, one row (mf) at a time
    unsigned short* outA = (unsigned short*)outP;
    unsigned short* slice = smem + w * 2048;
    #pragma unroll
    for (int mf = 0; mf < 4; ++mf) {
      int y = tY0 + pxg * ROWS_PG + mf;
      #pragma unroll
      for (int rr = 0; rr < 4; ++rr) {
        int x = 4 * kg + rr;
        #pragma unroll
        for (int nf = 0; nf < 4; ++nf) {
          float vv = fmaxf(acc[mf][nf][rr] * Ar[nf] + Cr[nf], 0.f);
          unsigned short h = f2bf(vv);
          unsigned short l = f2bf(vv - bf2f(h));
          slice[(x * 2 + 0) * 64 + nf * 16 + lx] = h;
          slice[(x * 2 + 1) * 64 + nf * 16 + lx] = l;
        }
      }
      #pragma unroll
      for (int v = 0; v < 4; ++v) {
        int hoff = lane * 8 + v * 512;
        int x2 = hoff >> 7, rem = hoff & 127;
        int seg = rem >> 6, inner = rem & 63;
        short8 d = *(const short8*)(slice + hoff);
        *(short8*)(outA + ((long)img * 256 + y * 16 + x2) * (2 * CO)
                   + seg * CO + blkco * COB + cog * 64 + inner) = d;
      }
    }
  } else if (MODE == 1) {
    // fused 2x2 maxpool store via per-wave 4KB transpose slice (1 pooled row)
    unsigned short* outA = (unsigned short*)outP;
    unsigned short* slice = smem + w * 2048;
    const int py = (tY0 >> 1) + pxg;
    #pragma unroll
    for (int xf = 0; xf < 2; ++xf) {
      #pragma unroll
      for (int rp = 0; rp < 2; ++rp) {
        int ox = xf * 8 + 2 * kg + rp;
        #pragma unroll
        for (int nf = 0; nf < 4; ++nf) {
          float v0 = fmaxf(fmaxf(acc[xf][nf][2 * rp], acc[xf][nf][2 * rp + 1]),
                           fmaxf(acc[xf + 2][nf][2 * rp], acc[xf + 2][nf][2 * rp + 1]));
          float vv = fmaxf(v0 * Ar[nf] + Cr[nf], 0.f);
          unsigned short h = f2bf(vv);
          unsigned short l = f2bf(vv - bf2f(h));
          slice[(ox * 2 + 0) * 64 + nf * 16 + lx] = h;
          slice[(ox * 2 + 1) * 64 + nf * 16 + lx] = l;
        }
      }
    }
    #pragma unroll
    for (int v = 0; v < 4; ++v) {
      int hoff = lane * 8 + v * 512;
      int x2 = hoff >> 7, rem = hoff & 127;
      int seg = rem >> 6, inner = rem & 63;
      short8 d = *(const short8*)(slice + hoff);
      *(short8*)(outA + ((long)img * 256 + py * 16 + x2) * (2 * CO)
                 + seg * CO + inner) = d;
    }
  } else {
    // MODE 2: 2x2 maxpool + BN/ReLU + global average -> feats
    float psum[4] = {0.f, 0.f, 0.f, 0.f};
    #pragma unroll
    for (int nf = 0; nf < 4; ++nf) {
      #pragma unroll
      for (int mfp = 0; mfp < 2; ++mfp) {
        #pragma unroll
        for (int rp = 0; rp < 2; ++rp) {
          float v = fmaxf(fmaxf(acc[2 * mfp][nf][2 * rp], acc[2 * mfp][nf][2 * rp + 1]),
                          fmaxf(acc[2 * mfp + 1][nf][2 * rp], acc[2 * mfp + 1][nf][2 * rp + 1]));
          psum[nf] += fmaxf(v * Ar[nf] + Cr[nf], 0.f);
        }
      }
    }
    #pragma unroll
    for (int nf = 0; nf < 4; ++nf) {
      psum[nf] += __shfl_xor(psum[nf], 16);
      psum[nf] += __shfl_xor(psum[nf], 32);
    }
    __syncthreads();
    float* sR = (float*)smem;
    if (kg == 0) {
      #pragma unroll
      for (int nf = 0; nf < 4; ++nf) sR[w * 64 + nf * 16 + lx] = psum[nf];
    }
    __syncthreads();
    if (tid < COB) {
      int ct = tid >> 6, ci_ = tid & 63;
      float s = 0.f;
      #pragma unroll
      for (int p = 0; p < NPXG; ++p) s += sR[(ct * NPXG + p) * 64 + ci_];
      ((float*)outP)[(long)img * 256 + blkco * COB + tid] = s * (1.f / 64.f);
    }
  }
}

// ---------------------------------------------------------------------------
// heads / sort / routing / combine (unchanged)
__global__ __launch_bounds__(256) void heads2_kernel(
    const float* __restrict__ feats, const float* __restrict__ gw1,
    const float* __restrict__ gb1, const float* __restrict__ gw2,
    const float* __restrict__ gb2, const float* __restrict__ clsw,
    const float* __restrict__ clsb, const float* __restrict__ usage,
    float* __restrict__ logits_e, float* __restrict__ rs_out)
{
  __shared__ float sF[64 * 257];
  __shared__ float sLg[4 * 64 * 10];
  __shared__ float sRed[4 * 64];
  const int tid = threadIdx.x;
  const int b0 = blockIdx.x * 64;
  const int e  = blockIdx.y;

  for (int idx = tid; idx < 64 * 64; idx += 256) {
    int t = idx >> 6, dg = idx & 63;
    float4 v = ((const float4*)(feats + (long)(b0 + t) * 256))[dg];
    float* p = sF + t * 257 + dg * 4;
    p[0] = v.x; p[1] = v.y; p[2] = v.z; p[3] = v.w;
  }
  __syncthreads();

  const int t  = tid & 63;
  const int hw = __builtin_amdgcn_readfirstlane(tid >> 6);

  {
    float acc[10];
    #pragma unroll
    for (int c = 0; c < 10; ++c) acc[c] = 0.f;
    const float* fp = sF + t * 257 + hw * 64;
    const float* cw = clsw + (long)e * 2560 + hw * 64;
    for (int dd = 0; dd < 64; ++dd) {
      float f = fp[dd];
      #pragma unroll
      for (int c = 0; c < 10; ++c) acc[c] += f * cw[c * 256 + dd];
    }
    #pragma unroll
    for (int c = 0; c < 10; ++c) sLg[(hw * 64 + t) * 10 + c] = acc[c];
  }
  {
    float gacc[32];
    #pragma unroll
    for (int j = 0; j < 32; ++j) gacc[j] = 0.f;
    const float* wb = gw1 + ((long)e * 256) * 128 + hw * 32;
    const float* fp = sF + t * 257;
    for (int d = 0; d < 256; ++d) {
      float f = fp[d];
      const float4* w4 = (const float4*)(wb + (long)d * 128);
      #pragma unroll
      for (int qq = 0; qq < 8; ++qq) {
        float4 wv = w4[qq];
        gacc[4 * qq + 0] += f * wv.x; gacc[4 * qq + 1] += f * wv.y;
        gacc[4 * qq + 2] += f * wv.z; gacc[4 * qq + 3] += f * wv.w;
      }
    }
    float s = 0.f;
    const float* b1 = gb1 + e * 128 + hw * 32;
    const float* w2 = gw2 + e * 128 + hw * 32;
    #pragma unroll
    for (int j = 0; j < 32; ++j) s += fmaxf(gacc[j] + b1[j], 0.f) * w2[j];
    sRed[hw * 64 + t] = s;
  }
  __syncthreads();

  if (tid < 64) {
    float es = (sRed[t] + sRed[64 + t] + sRed[128 + t] + sRed[192 + t] + gb2[e]) * 0.5f;
    float lg[10];
    #pragma unroll
    for (int c = 0; c < 10; ++c)
      lg[c] = sLg[t * 10 + c] + sLg[(64 + t) * 10 + c]
            + sLg[(128 + t) * 10 + c] + sLg[(192 + t) * 10 + c] + clsb[e * 10 + c];
    float mx = lg[0];
    #pragma unroll
    for (int c = 1; c < 10; ++c) mx = fmaxf(mx, lg[c]);
    float S = 0.f, ps[10];
    #pragma unroll
    for (int c = 0; c < 10; ++c) { ps[c] = expf(lg[c] - mx); S += ps[c]; }
    float inv = 1.f / S, ent = 0.f;
    #pragma unroll
    for (int c = 0; c < 10; ++c) { float p = ps[c] * inv; ent -= p * logf(fmaxf(p, 1e-12f)); }
    float rsv = 0.6f * es + 0.4f * (-ent) - 2.0f * usage[e];
    rs_out[(long)(b0 + t) * 16 + e] = rsv;
    #pragma unroll
    for (int c = 0; c < 10; ++c)
      logits_e[((long)(b0 + t) * 16 + e) * 10 + c] = lg[c];
  }
}

__global__ __launch_bounds__(1024) void sort_kernel(
    const float* __restrict__ rs, unsigned* __restrict__ sortedIdx)
{
  __shared__ unsigned long long sk[2048];
  const int e = blockIdx.x;
  const unsigned tid = threadIdx.x;
  for (int i = tid; i < 2048; i += 1024) {
    float f = rs[(long)i * 16 + e];
    unsigned u = __float_as_uint(f);
    u ^= (u >> 31) ? 0xFFFFFFFFu : 0x80000000u;
    sk[i] = ((unsigned long long)(~u) << 32) | (unsigned)i;
  }
  for (unsigned k = 2; k <= 2048; k <<= 1) {
    for (unsigned j = k >> 1; j > 0; j >>= 1) {
      __syncthreads();
      unsigned i = ((tid & ~(j - 1)) << 1) | (tid & (j - 1));
      unsigned p = i | j;
      bool asc = ((i & k) == 0);
      unsigned long long a = sk[i], b = sk[p];
      if ((a > b) == asc) { sk[i] = b; sk[p] = a; }
    }
  }
  __syncthreads();
  for (int i = tid; i < 2048; i += 1024)
    sortedIdx[(long)e * 2048 + i] = (unsigned)(sk[i] & 0xFFFFFFFFull);
}

__global__ __launch_bounds__(1024) void routing_kernel(
    const unsigned* __restrict__ sortedIdx, const float* __restrict__ rs,
    float* __restrict__ Dout, unsigned* __restrict__ dmaskOut)
{
  __shared__ unsigned char sAvail[2048];
  __shared__ unsigned sDm[2048];
  __shared__ int sLoads[16];
  __shared__ int sWaveCnt[16];
  __shared__ int sNtc, sVC;
  const int tid = threadIdx.x;
  const int lane = tid & 63, wave = tid >> 6;
  for (int i = tid; i < 2048; i += 1024) { sAvail[i] = 1; sDm[i] = 0; }
  if (tid < 16) sLoads[tid] = 0;
  if (tid == 0) sVC = 2048;
  __syncthreads();
  for (int it = 0; it < 3; ++it) {
    for (int j = 0; j < 16; ++j) {
      if (tid == 0) {
        int rc = 256 - sLoads[j]; if (rc < 0) rc = 0;
        int vc = sVC, ntc = 0;
        if (rc > 0 && vc > 0) {
          int a = rc < vc ? rc : vc;
          int b2 = vc < 102 ? vc : 102;
          ntc = a > b2 ? a : b2;
        }
        sNtc = ntc; sLoads[j] += ntc; sVC -= ntc;
      }
      __syncthreads();
      const int ntc = sNtc;
      if (ntc > 0) {
        int base = 0;
        for (int p = 0; p < 2; ++p) {
          int i = p * 1024 + tid;
          unsigned tok = sortedIdx[(long)j * 2048 + i];
          int fl = sAvail[tok] ? 1 : 0;
          unsigned long long bm = __ballot(fl);
          if (lane == 0) sWaveCnt[wave] = __popcll(bm);
          __syncthreads();
          int off = base;
          for (int w = 0; w < wave; ++w) off += sWaveCnt[w];
          int pre = off + __popcll(bm & ((1ull << lane) - 1ull));
          if (fl && pre < ntc) { sAvail[tok] = 0; sDm[tok] |= (1u << j); }
          int tot = base;
          for (int w = 0; w < 16; ++w) tot += sWaveCnt[w];
          base = tot;
          __syncthreads();
        }
      }
      __syncthreads();
    }
  }
  if (tid == 0 && sVC > 0) {
    for (int i = 0; i < 2048; ++i) {
      if (!sAvail[i]) continue;
      float s0 = -3.4e38f, s1 = s0, s2 = s0; int e0 = 0, e1 = 0, e2 = 0;
      for (int e = 0; e < 16; ++e) {
        float s = rs[i * 16 + e];
        if (s > s0)      { s2 = s1; e2 = e1; s1 = s0; e1 = e0; s0 = s; e0 = e; }
        else if (s > s1) { s2 = s1; e2 = e1; s1 = s;  e1 = e; }
        else if (s > s2) { s2 = s;  e2 = e; }
      }
      int best = e0, bl = sLoads[e0];
      if (sLoads[e1] < bl) { best = e1; bl = sLoads[e1]; }
      if (sLoads[e2] < bl) { best = e2; bl = sLoads[e2]; }
      sDm[i] |= (1u << best);
      sLoads[best] += 1;
    }
  }
  __syncthreads();
  for (int idx = tid; idx < 2048 * 16; idx += 1024) {
    int tok = idx >> 4, e = idx & 15;
    Dout[idx] = ((sDm[tok] >> e) & 1u) ? 1.0f : 0.0f;
  }
  for (int i = tid; i < 2048; i += 1024) dmaskOut[i] = sDm[i];
}

__global__ __launch_bounds__(256) void combine_kernel(
    const unsigned* __restrict__ dmask, const float* __restrict__ rs,
    const float* __restrict__ L, float* __restrict__ out)
{
  int i = blockIdx.x * 256 + threadIdx.x;
  if (i >= 2048) return;
  unsigned dm = dmask[i];
  float r[16];
  #pragma unroll
  for (int e = 0; e < 16; ++e) r[e] = rs[i * 16 + e];
  float mx = -3.4e38f;
  #pragma unroll
  for (int e = 0; e < 16; ++e) {
    float v = ((dm >> e) & 1u) ? r[e] : 0.0f;
    mx = fmaxf(mx, v);
  }
  float w[16], S = 0.f;
  #pragma unroll
  for (int e = 0; e < 16; ++e) {
    w[e] = ((dm >> e) & 1u) ? expf(r[e] - mx) : 0.0f;
    S += w[e];
  }
  float inv = 1.f / S;
  #pragma unroll
  for (int c = 0; c < 10; ++c) {
    float a = 0.f;
    #pragma unroll
    for (int e = 0; e < 16; ++e) a += w[e] * L[((long)i * 16 + e) * 10 + c];
    out[i * 10 + c] = a * inv;
  }
}

// ---------------------------------------------------------------------------
extern "C" void kernel_launch(void* const* d_in, const int* in_sizes, int n_in,
                              void* d_out, int out_size, void* d_ws, size_t ws_size,
                              hipStream_t stream)
{
  const float* x    = (const float*)d_in[0];
  const float* cw1  = (const float*)d_in[1];
  const float* cb1  = (const float*)d_in[2];
  const float* g1   = (const float*)d_in[3];
  const float* be1  = (const float*)d_in[4];
  const float* m1   = (const float*)d_in[5];
  const float* v1   = (const float*)d_in[6];
  const float* cw2  = (const float*)d_in[7];
  const float* cb2  = (const float*)d_in[8];
  const float* g2   = (const float*)d_in[9];
  const float* be2  = (const float*)d_in[10];
  const float* m2   = (const float*)d_in[11];
  const float* v2   = (const float*)d_in[12];
  const float* cw3  = (const float*)d_in[13];
  const float* cb3  = (const float*)d_in[14];
  const float* g3   = (const float*)d_in[15];
  const float* be3  = (const float*)d_in[16];
  const float* m3   = (const float*)d_in[17];
  const float* v3   = (const float*)d_in[18];
  const float* cw4  = (const float*)d_in[19];
  const float* cb4  = (const float*)d_in[20];
  const float* g4   = (const float*)d_in[21];
  const float* be4  = (const float*)d_in[22];
  const float* m4   = (const float*)d_in[23];
  const float* v4   = (const float*)d_in[24];
  const float* gw1  = (const float*)d_in[25];
  const float* gb1  = (const float*)d_in[26];
  const float* gw2  = (const float*)d_in[27];
  const float* gb2  = (const float*)d_in[28];
  const float* clsw = (const float*)d_in[29];
  const float* clsb = (const float*)d_in[30];
  const float* usage = (const float*)d_in[31];

  float* out = (float*)d_out;
  float* ws  = (float*)d_ws;

  float* A1 = ws + 0;   float* C1 = ws + 32;
  float* A2 = ws + 64;  float* C2 = ws + 128;
  float* A3 = ws + 192; float* C3 = ws + 320;
  float* A4 = ws + 448; float* C4 = ws + 704;
  float* feats   = ws + 1024;                       // 2048*256
  float* logitsE = ws + 525312;                     // 2048*16*10
  unsigned* sortedIdx = (unsigned*)(ws + 852992);   // 16*2048
  unsigned* dmask     = (unsigned*)(ws + 885760);   // 2048
  unsigned short* wPk2 = (unsigned short*)(ws + 887808);   // 36 units  * 1024 halves
  unsigned short* wPk3 = (unsigned short*)(ws + 906240);   // 144 units * 1024
  unsigned short* wPk4 = (unsigned short*)(ws + 979968);   // 576 units * 1024
  const long bufBase = 1274880;

  long wsFloats = (long)(ws_size / 4);
  long availF = wsFloats - bufBase;
  long chunkL = availF / 49152;   // per-img: bufA 32768 f + bufB 16384 f
  int chunk = (int)(chunkL < 1 ? 1 : (chunkL > 2048 ? 2048 : chunkL));

  bnprep_kernel<<<1, 256, 0, stream>>>(g1, be1, m1, v1, cb1, A1, C1, 32);
  bnprep_kernel<<<1, 256, 0, stream>>>(g2, be2, m2, v2, cb2, A2, C2, 64);
  bnprep_kernel<<<1, 256, 0, stream>>>(g3, be3, m3, v3, cb3, A3, C3, 128);
  bnprep_kernel<<<1, 256, 0, stream>>>(g4, be4, m4, v4, cb4, A4, C4, 256);
  wprep2_kernel<<<(2304 + 255) / 256, 256, 0, stream>>>(cw2, wPk2, 64, 32);
  wprep2_kernel<<<(9216 + 255) / 256, 256, 0, stream>>>(cw3, wPk3, 128, 64);
  wprep2_kernel<<<(36864 + 255) / 256, 256, 0, stream>>>(cw4, wPk4, 256, 128);

  unsigned short* bufA = (unsigned short*)(ws + bufBase);
  unsigned short* bufB = bufA + (long)chunk * 65536;

  for (int ib = 0; ib < 2048; ib += chunk) {
    int n = 2048 - ib; if (n > chunk) n = chunk;
    conv1_kernel<<<dim3(n, 4), 256, 0, stream>>>(x + (long)ib * 3072, cw1, A1, C1, bufA);
    // conv2: 32x32, 32->64ch, 2 y-tiles/img, all 64 co, fused maxpool -> act2
    convmf4_kernel<32, 32, 64, 64, 16, 32, 1>
        <<<dim3(n * 2), 512, 0, stream>>>(bufA, wPk2, A2, C2, bufB);
    // conv3: 16x16, 64->128ch, 1 block/img (no co-split), plain store -> act3
    convmf4_kernel<16, 64, 128, 128, 16, 16, 0>
        <<<dim3(n), 512, 0, stream>>>(bufB, wPk3, A3, C3, bufA);
    // conv4: 16x16, 128->256ch, 2 co-blocks/img, pool+avg -> feats
    convmf4_kernel<16, 128, 256, 128, 16, 16, 2>
        <<<dim3(n * 2), 512, 0, stream>>>(bufA, wPk4, A4, C4, feats + (long)ib * 256);
  }

  float* rsOut = out + 20480;
  heads2_kernel<<<dim3(32, 16), 256, 0, stream>>>(feats, gw1, gb1, gw2, gb2,
                                                  clsw, clsb, usage, logitsE, rsOut);
  sort_kernel<<<16, 1024, 0, stream>>>(rsOut, sortedIdx);
  routing_kernel<<<1, 1024, 0, stream>>>(sortedIdx, rsOut, out + 53248, dmask);
  combine_kernel<<<8, 256, 0, stream>>>(dmask, rsOut, logitsE, out);
}